// Round 2
// baseline (1515.693 us; speedup 1.0000x reference)
//
#include <hip/hip_runtime.h>
#include <hip/hip_bf16.h>
#include <math.h>

typedef __hip_bfloat16 bf16;

#define HW 16384          // 128*128
#define NSLICE 243        // 9*9*3

// ---- band tables (anti-diagonals of 9x9 grid) ----
__constant__ int c_s_of_p[81] = {
  0, 1,1, 2,2,2, 3,3,3,3, 4,4,4,4,4, 5,5,5,5,5,5, 6,6,6,6,6,6,6,
  7,7,7,7,7,7,7,7, 8,8,8,8,8,8,8,8,8, 9,9,9,9,9,9,9,9,
  10,10,10,10,10,10,10, 11,11,11,11,11,11, 12,12,12,12,12,
  13,13,13,13, 14,14,14, 15,15, 16};
__constant__ int c_l_of_p[81] = {
  0, 0,1, 0,1,2, 0,1,2,3, 0,1,2,3,4, 0,1,2,3,4,5, 0,1,2,3,4,5,6,
  0,1,2,3,4,5,6,7, 0,1,2,3,4,5,6,7,8, 0,1,2,3,4,5,6,7,
  0,1,2,3,4,5,6, 0,1,2,3,4,5, 0,1,2,3,4, 0,1,2,3, 0,1,2, 0,1, 0};
__constant__ int c_L_of_s[17] = {1,2,3,4,5,6,7,8,9,8,7,6,5,4,3,2,1};
__constant__ int c_g_of_s[17] = {0,1,1,2,2,2,2,2,2,3,3,3,3,3,3,3,3};
// p index for flattened (u*9+v)
__constant__ int c_pos_uv[81] = {
  0,1,3,6,10,15,21,28,36,
  2,4,7,11,16,22,29,37,45,
  5,8,12,17,23,30,38,46,53,
  9,13,18,24,31,39,47,54,60,
  14,19,25,32,40,48,55,61,66,
  20,26,33,41,49,56,62,67,71,
  27,34,42,50,57,63,68,72,75,
  35,43,51,58,64,69,73,76,78,
  44,52,59,65,70,74,77,79,80};

struct WPtrs {
  const float* wi[4]; const float* bi[4]; const float* a[4];
  const float* wb[4]; const float* bb[4]; const float* wl;
};

// ---- setup: DCT matrices + 81x81 angular Kronecker table ----
__global__ __launch_bounds__(256) void k_setup(float* dctS, float* dctSt,
                                               float* T81, float* T81t) {
  const double PI = 3.14159265358979323846;
  int t = threadIdx.x;
  for (int idx = t; idx < 128 * 128; idx += 256) {
    int k = idx >> 7, i = idx & 127;
    double m = cos(PI * (i + 0.5) * k / 128.0) * sqrt(2.0 / 128.0);
    if (k == 0) m *= (1.0 / sqrt(2.0));
    dctS[k * 128 + i] = (float)m;
    dctSt[i * 128 + k] = (float)m;
  }
  for (int idx = t; idx < 6561; idx += 256) {
    int al = idx / 81, be = idx % 81;
    int Uu = al / 9, Vv = al % 9, uu = be / 9, vv = be % 9;
    double d1 = cos(PI * (uu + 0.5) * Uu / 9.0) * sqrt(2.0 / 9.0);
    if (Uu == 0) d1 *= (1.0 / sqrt(2.0));
    double d2 = cos(PI * (vv + 0.5) * Vv / 9.0) * sqrt(2.0 / 9.0);
    if (Vv == 0) d2 *= (1.0 / sqrt(2.0));
    float tv = (float)(d1 * d2);
    T81[al * 81 + be] = tv;     // forward: out[alpha] = sum_beta T * in[beta]
    T81t[be * 81 + al] = tv;    // inverse: out[beta] = sum_alpha T * in[alpha]
  }
}

// ---- weight repack: layout [cin][dz][ky][kx][cout] ----
__global__ __launch_bounds__(256) void k_prep(WPtrs P, float* WiF, float* WbF,
                                              float* BiF, float* BbF,
                                              float* AF, float* WlF) {
  int t = blockIdx.x * 256 + threadIdx.x;
  if (t < 5184) {  // Wi: [g][cin][tap][cout], g*1296
    int g = t / 1296, r = t % 1296;
    int cout = r % 16, r2 = r / 16;
    int tap = r2 % 27, cin = r2 / 27;
    WiF[t] = P.wi[g][(cout * 3 + cin) * 27 + tap];
  }
  if (t < 55296) {  // Wb: [g][k][cin][tap][cout]
    int g = t / 13824, r = t % 13824;
    int k = r / 6912, r2 = r % 6912;
    int cout = r2 % 16, r3 = r2 / 16;
    int tap = r3 % 27, cin = r3 / 27;
    WbF[t] = P.wb[g][((k * 16 + cout) * 16 + cin) * 27 + tap];
  }
  if (t < 64)  BiF[t] = P.bi[t / 16][t % 16];
  if (t < 128) BbF[t] = P.bb[t / 32][t % 32];
  if (t < 8)   AF[t]  = P.a[t / 2][t % 2];
  if (t < 48)  WlF[t] = P.wl[t];
}

// ---- batched 128x128 left/right multiplies (spatial DCT stages) ----
// Y[s][i][w] = sum_h W[h*128+i] * X[s][h][w]
__global__ __launch_bounds__(256) void k_lmul(const float* __restrict__ X,
                                              const float* __restrict__ W,
                                              float* __restrict__ Y) {
  int w = threadIdx.x & 127;
  int ih = threadIdx.x >> 7;
  int s = blockIdx.x;
  int i0 = blockIdx.y * 32 + ih * 16;
  const float* Xs = X + (size_t)s * HW;
  float acc[16];
#pragma unroll
  for (int k = 0; k < 16; k++) acc[k] = 0.f;
  for (int h = 0; h < 128; h++) {
    float xv = Xs[h * 128 + w];
    const float4* wr = (const float4*)(W + h * 128 + i0);
    float4 w0 = wr[0], w1 = wr[1], w2 = wr[2], w3 = wr[3];
    acc[0] += xv * w0.x;  acc[1] += xv * w0.y;  acc[2] += xv * w0.z;  acc[3] += xv * w0.w;
    acc[4] += xv * w1.x;  acc[5] += xv * w1.y;  acc[6] += xv * w1.z;  acc[7] += xv * w1.w;
    acc[8] += xv * w2.x;  acc[9] += xv * w2.y;  acc[10] += xv * w2.z; acc[11] += xv * w2.w;
    acc[12] += xv * w3.x; acc[13] += xv * w3.y; acc[14] += xv * w3.z; acc[15] += xv * w3.w;
  }
  float* Yo = Y + (size_t)s * HW + w;
#pragma unroll
  for (int k = 0; k < 16; k++) Yo[(i0 + k) * 128] = acc[k];
}

// Y[s][h][j] = sum_w X[s][h][w] * W2[w*128+j]
__global__ __launch_bounds__(256) void k_rmul(const float* __restrict__ X,
                                              const float* __restrict__ W2,
                                              float* __restrict__ Y) {
  int j = threadIdx.x & 127;
  int jh = threadIdx.x >> 7;
  int s = blockIdx.x;
  int h0 = blockIdx.y * 32 + jh * 16;
  const float* Xs = X + (size_t)s * HW;
  float acc[16];
#pragma unroll
  for (int k = 0; k < 16; k++) acc[k] = 0.f;
  for (int w = 0; w < 128; w++) {
    float wv = W2[w * 128 + j];
#pragma unroll
    for (int k = 0; k < 16; k++) acc[k] += Xs[(h0 + k) * 128 + w] * wv;
  }
  float* Yo = Y + (size_t)s * HW;
#pragma unroll
  for (int k = 0; k < 16; k++) Yo[(h0 + k) * 128 + j] = acc[k];
}

// same as k_rmul + add original x, write fp32 output
__global__ __launch_bounds__(256) void k_rmul_add(const float* __restrict__ X,
                                                  const float* __restrict__ W2,
                                                  const float* __restrict__ xin,
                                                  float* __restrict__ out) {
  int j = threadIdx.x & 127;
  int jh = threadIdx.x >> 7;
  int s = blockIdx.x;
  int h0 = blockIdx.y * 32 + jh * 16;
  const float* Xs = X + (size_t)s * HW;
  float acc[16];
#pragma unroll
  for (int k = 0; k < 16; k++) acc[k] = 0.f;
  for (int w = 0; w < 128; w++) {
    float wv = W2[w * 128 + j];
#pragma unroll
    for (int k = 0; k < 16; k++) acc[k] += Xs[(h0 + k) * 128 + w] * wv;
  }
#pragma unroll
  for (int k = 0; k < 16; k++) {
    size_t oi = (size_t)s * HW + (h0 + k) * 128 + j;
    out[oi] = acc[k] + xin[oi];
  }
}

// ---- angular DCT forward: xf1[slice(u,v,c)][hw] -> banded xf2[p][c][hw] ----
__global__ __launch_bounds__(256) void k_ang_fwd(const float* __restrict__ xf1,
                                                 const float* __restrict__ T81,
                                                 float* __restrict__ xf2) {
  int idx = blockIdx.x * 256 + threadIdx.x;   // 27*HW total
  int hw = idx & (HW - 1);
  int r = idx >> 14;            // 0..26
  int c = r % 3, og = r / 3;    // output group og covers alpha = og*9..og*9+8
  float f[81];
#pragma unroll
  for (int b = 0; b < 81; b++) f[b] = xf1[(size_t)(b * 3 + c) * HW + hw];
  for (int a = 0; a < 9; a++) {
    int al = og * 9 + a;
    const float* Tr = T81 + al * 81;
    float acc = 0.f;
#pragma unroll
    for (int b = 0; b < 81; b++) acc += Tr[b] * f[b];
    xf2[((size_t)c_pos_uv[al] * 3 + c) * HW + hw] = acc;
  }
}

// ---- angular DCT inverse: banded xrb[p][c][hw] -> xr2[slice(u,v,c)][hw] ----
__global__ __launch_bounds__(256) void k_ang_inv(const float* __restrict__ xrb,
                                                 const float* __restrict__ T81t,
                                                 float* __restrict__ xr2) {
  int idx = blockIdx.x * 256 + threadIdx.x;
  int hw = idx & (HW - 1);
  int r = idx >> 14;
  int c = r % 3, og = r / 3;
  float f[81];
#pragma unroll
  for (int al = 0; al < 81; al++)
    f[al] = xrb[((size_t)c_pos_uv[al] * 3 + c) * HW + hw];
  for (int a = 0; a < 9; a++) {
    int be = og * 9 + a;
    const float* Tr = T81t + be * 81;
    float acc = 0.f;
#pragma unroll
    for (int al = 0; al < 81; al++) acc += Tr[al] * f[al];
    xr2[((size_t)be * 3 + c) * HW + hw] = acc;
  }
}

// ---- init conv: 3->16, 3x3x3 SAME over band volume ----
__global__ __launch_bounds__(512) void k_conv_init(const float* __restrict__ xin,
                                                   const float* __restrict__ WiF,
                                                   const float* __restrict__ BiF,
                                                   bf16* __restrict__ bout) {
  __shared__ float wlds[3 * 27 * 16];
  __shared__ float blds[16];
  int p = blockIdx.y;
  int s = c_s_of_p[p], l = c_l_of_p[p];
  int g = c_g_of_s[s], Ls = c_L_of_s[s];
  int t = threadIdx.x;
  for (int i = t; i < 1296; i += 512) wlds[i] = WiF[g * 1296 + i];
  if (t < 16) blds[t] = BiF[g * 16 + t];
  __syncthreads();
  int w = t & 127, q = t >> 7;
  int h0 = blockIdx.x * 4 + (q & 1) * 2;
  int co0 = (q >> 1) * 8;
  float acc[2][8];
#pragma unroll
  for (int j = 0; j < 2; j++)
#pragma unroll
    for (int o = 0; o < 8; o++) acc[j][o] = 0.f;
#pragma unroll 1
  for (int dz = 0; dz < 3; dz++) {
    int l2 = l + dz - 1;
    if (l2 < 0 || l2 >= Ls) continue;
    const float* ibase = xin + (size_t)(p + dz - 1) * 3 * HW;
#pragma unroll 1
    for (int cin = 0; cin < 3; cin++) {
      const float* ip = ibase + cin * HW;
      float iv[4][3];
#pragma unroll
      for (int rr = 0; rr < 4; rr++) {
        int hh = h0 - 1 + rr;
        bool hv = (hh >= 0) && (hh < 128);
#pragma unroll
        for (int cc = 0; cc < 3; cc++) {
          int ww = w - 1 + cc;
          iv[rr][cc] = (hv && ww >= 0 && ww < 128) ? ip[hh * 128 + ww] : 0.f;
        }
      }
      const float* wb = wlds + (cin * 27 + dz * 9) * 16;
#pragma unroll
      for (int ky = 0; ky < 3; ky++) {
#pragma unroll
        for (int kx = 0; kx < 3; kx++) {
          const float4* wv = (const float4*)(wb + (ky * 3 + kx) * 16 + co0);
          float4 wa = wv[0], wc = wv[1];
#pragma unroll
          for (int j = 0; j < 2; j++) {
            float v = iv[j + ky][kx];
            acc[j][0] += v * wa.x; acc[j][1] += v * wa.y;
            acc[j][2] += v * wa.z; acc[j][3] += v * wa.w;
            acc[j][4] += v * wc.x; acc[j][5] += v * wc.y;
            acc[j][6] += v * wc.z; acc[j][7] += v * wc.w;
          }
        }
      }
    }
  }
#pragma unroll
  for (int j = 0; j < 2; j++)
#pragma unroll
    for (int o = 0; o < 8; o++)
      bout[((size_t)p * 16 + co0 + o) * HW + (h0 + j) * 128 + w] =
          __float2bfloat16(acc[j][o] + blds[co0 + o]);
}

// ---- ResBlock conv: out = prev + bias + conv3d(prelu(prev)) ----
__global__ __launch_bounds__(512) void k_conv_res(const bf16* __restrict__ bin,
                                                  const float* __restrict__ WbF,
                                                  const float* __restrict__ BbF,
                                                  const float* __restrict__ AF,
                                                  int kblk, bf16* __restrict__ bout) {
  __shared__ float wlds[16 * 27 * 16];
  __shared__ float blds[16];
  __shared__ float s_alpha;
  int p = blockIdx.y;
  int s = c_s_of_p[p], l = c_l_of_p[p];
  int g = c_g_of_s[s], Ls = c_L_of_s[s];
  int t = threadIdx.x;
  for (int i = t; i < 6912; i += 512) wlds[i] = WbF[(g * 2 + kblk) * 6912 + i];
  if (t < 16) blds[t] = BbF[(g * 2 + kblk) * 16 + t];
  if (t == 511) s_alpha = AF[g * 2 + kblk];
  __syncthreads();
  float alpha = s_alpha;
  int w = t & 127, q = t >> 7;
  int h0 = blockIdx.x * 4 + (q & 1) * 2;
  int co0 = (q >> 1) * 8;
  float acc[2][8];
#pragma unroll
  for (int j = 0; j < 2; j++)
#pragma unroll
    for (int o = 0; o < 8; o++) acc[j][o] = 0.f;
#pragma unroll 1
  for (int dz = 0; dz < 3; dz++) {
    int l2 = l + dz - 1;
    if (l2 < 0 || l2 >= Ls) continue;
    const bf16* ibase = bin + (size_t)(p + dz - 1) * 16 * HW;
#pragma unroll 1
    for (int cin = 0; cin < 16; cin++) {
      const bf16* ip = ibase + (size_t)cin * HW;
      float iv[4][3];
#pragma unroll
      for (int rr = 0; rr < 4; rr++) {
        int hh = h0 - 1 + rr;
        bool hv = (hh >= 0) && (hh < 128);
#pragma unroll
        for (int cc = 0; cc < 3; cc++) {
          int ww = w - 1 + cc;
          float v = 0.f;
          if (hv && ww >= 0 && ww < 128) {
            float raw = __bfloat162float(ip[hh * 128 + ww]);
            v = (raw >= 0.f) ? raw : alpha * raw;   // fused PReLU
          }
          iv[rr][cc] = v;
        }
      }
      const float* wb = wlds + (cin * 27 + dz * 9) * 16;
#pragma unroll
      for (int ky = 0; ky < 3; ky++) {
#pragma unroll
        for (int kx = 0; kx < 3; kx++) {
          const float4* wv = (const float4*)(wb + (ky * 3 + kx) * 16 + co0);
          float4 wa = wv[0], wc = wv[1];
#pragma unroll
          for (int j = 0; j < 2; j++) {
            float v = iv[j + ky][kx];
            acc[j][0] += v * wa.x; acc[j][1] += v * wa.y;
            acc[j][2] += v * wa.z; acc[j][3] += v * wa.w;
            acc[j][4] += v * wc.x; acc[j][5] += v * wc.y;
            acc[j][6] += v * wc.z; acc[j][7] += v * wc.w;
          }
        }
      }
    }
  }
#pragma unroll
  for (int j = 0; j < 2; j++)
#pragma unroll
    for (int o = 0; o < 8; o++) {
      size_t oi = ((size_t)p * 16 + co0 + o) * HW + (h0 + j) * 128 + w;
      float prev = __bfloat162float(bin[oi]);       // residual (pre-activation)
      bout[oi] = __float2bfloat16(prev + blds[co0 + o] + acc[j][o]);
    }
}

// ---- epilogue: xrb[p][c][hw] = sum_n wlast[c][n]*(b0+b2)  (1x1 conv folded) ----
__global__ __launch_bounds__(256) void k_epi(const bf16* __restrict__ b0,
                                             const bf16* __restrict__ b2,
                                             const float* __restrict__ WlF,
                                             float* __restrict__ xrb) {
  int idx = blockIdx.x * 256 + threadIdx.x;  // 81*HW
  int hw = idx & (HW - 1);
  int p = idx >> 14;
  float a0 = 0.f, a1 = 0.f, a2 = 0.f;
#pragma unroll
  for (int n = 0; n < 16; n++) {
    size_t ii = ((size_t)p * 16 + n) * HW + hw;
    float v = __bfloat162float(b0[ii]) + __bfloat162float(b2[ii]);
    a0 += WlF[n] * v; a1 += WlF[16 + n] * v; a2 += WlF[32 + n] * v;
  }
  xrb[((size_t)p * 3 + 0) * HW + hw] = a0;
  xrb[((size_t)p * 3 + 1) * HW + hw] = a1;
  xrb[((size_t)p * 3 + 2) * HW + hw] = a2;
}

extern "C" void kernel_launch(void* const* d_in, const int* in_sizes, int n_in,
                              void* d_out, int out_size, void* d_ws, size_t ws_size,
                              hipStream_t stream) {
  (void)in_sizes; (void)n_in; (void)out_size; (void)ws_size;
  const float* x = (const float*)d_in[0];
  WPtrs P;
  for (int g = 0; g < 4; g++) {
    int b = 1 + g * 5;
    P.wi[g] = (const float*)d_in[b + 0];
    P.bi[g] = (const float*)d_in[b + 1];
    P.a[g]  = (const float*)d_in[b + 2];
    P.wb[g] = (const float*)d_in[b + 3];
    P.bb[g] = (const float*)d_in[b + 4];
  }
  P.wl = (const float*)d_in[21];

  char* base = (char*)d_ws;
  size_t off = 0;
  auto take = [&](size_t bytes) -> char* {
    char* r = base + off;
    off += (bytes + 255) & ~(size_t)255;
    return r;
  };
  float* dctS  = (float*)take(65536);
  float* dctSt = (float*)take(65536);
  float* T81   = (float*)take(26244);
  float* T81t  = (float*)take(26244);
  float* WiF   = (float*)take(5184 * 4);
  float* WbF   = (float*)take(55296 * 4);
  float* BiF   = (float*)take(256);
  float* BbF   = (float*)take(512);
  float* AF    = (float*)take(32);
  float* WlF   = (float*)take(192);
  // three fp32 slice buffers, reused by liveness
  float* F0 = (float*)take((size_t)NSLICE * HW * 4);
  float* F1 = (float*)take((size_t)NSLICE * HW * 4);
  float* F2 = (float*)take((size_t)NSLICE * HW * 4);
  bf16* b0 = (bf16*)take((size_t)81 * 16 * HW * 2);
  bf16* b1 = (bf16*)take((size_t)81 * 16 * HW * 2);
  bf16* b2 = (bf16*)take((size_t)81 * 16 * HW * 2);

  k_setup<<<1, 256, 0, stream>>>(dctS, dctSt, T81, T81t);
  k_prep<<<216, 256, 0, stream>>>(P, WiF, WbF, BiF, BbF, AF, WlF);
  // forward spatial DCT: F0 = Ds * X ; F1 = F0 * Ds^T
  k_lmul<<<dim3(243, 4), 256, 0, stream>>>(x, dctSt, F0);
  k_rmul<<<dim3(243, 4), 256, 0, stream>>>(F0, dctSt, F1);
  // forward angular DCT + band gather -> F2[p][c][hw]
  k_ang_fwd<<<1728, 256, 0, stream>>>(F1, T81, F2);
  // branch convs
  k_conv_init<<<dim3(32, 81), 512, 0, stream>>>(F2, WiF, BiF, b0);
  k_conv_res<<<dim3(32, 81), 512, 0, stream>>>(b0, WbF, BbF, AF, 0, b1);
  k_conv_res<<<dim3(32, 81), 512, 0, stream>>>(b1, WbF, BbF, AF, 1, b2);
  // (y0 + y2) then folded 1x1 conv -> F0[p][c][hw]
  k_epi<<<5184, 256, 0, stream>>>(b0, b2, WlF, F0);
  // inverse angular DCT (band scatter back) -> F1[slice][hw]
  k_ang_inv<<<1728, 256, 0, stream>>>(F0, T81t, F1);
  // inverse spatial DCT + residual add, fp32 out
  k_lmul<<<dim3(243, 4), 256, 0, stream>>>(F1, dctS, F2);
  k_rmul_add<<<dim3(243, 4), 256, 0, stream>>>(F2, dctS, x, (float*)d_out);
}

// Round 3
// 659.513 us; speedup vs baseline: 2.2982x; 2.2982x over previous
//
#include <hip/hip_runtime.h>
#include <hip/hip_bf16.h>
#include <math.h>

typedef __hip_bfloat16 bf16;
typedef __attribute__((ext_vector_type(8))) short short8;
typedef __attribute__((ext_vector_type(4))) float floatx4;
typedef __attribute__((ext_vector_type(4))) unsigned int uint4v;
typedef __attribute__((ext_vector_type(2))) unsigned int uint2v;

#define HW 16384          // 128*128
#define NSLICE 243        // 9*9*3

// ---- band tables (anti-diagonals of 9x9 grid) ----
__constant__ int c_s_of_p[81] = {
  0, 1,1, 2,2,2, 3,3,3,3, 4,4,4,4,4, 5,5,5,5,5,5, 6,6,6,6,6,6,6,
  7,7,7,7,7,7,7,7, 8,8,8,8,8,8,8,8,8, 9,9,9,9,9,9,9,9,
  10,10,10,10,10,10,10, 11,11,11,11,11,11, 12,12,12,12,12,
  13,13,13,13, 14,14,14, 15,15, 16};
__constant__ int c_l_of_p[81] = {
  0, 0,1, 0,1,2, 0,1,2,3, 0,1,2,3,4, 0,1,2,3,4,5, 0,1,2,3,4,5,6,
  0,1,2,3,4,5,6,7, 0,1,2,3,4,5,6,7,8, 0,1,2,3,4,5,6,7,
  0,1,2,3,4,5,6, 0,1,2,3,4,5, 0,1,2,3,4, 0,1,2,3, 0,1,2, 0,1, 0};
__constant__ int c_L_of_s[17] = {1,2,3,4,5,6,7,8,9,8,7,6,5,4,3,2,1};
__constant__ int c_g_of_s[17] = {0,1,1,2,2,2,2,2,2,3,3,3,3,3,3,3,3};
__constant__ int c_pos_uv[81] = {
  0,1,3,6,10,15,21,28,36,
  2,4,7,11,16,22,29,37,45,
  5,8,12,17,23,30,38,46,53,
  9,13,18,24,31,39,47,54,60,
  14,19,25,32,40,48,55,61,66,
  20,26,33,41,49,56,62,67,71,
  27,34,42,50,57,63,68,72,75,
  35,43,51,58,64,69,73,76,78,
  44,52,59,65,70,74,77,79,80};

struct WPtrs {
  const float* wi[4]; const float* bi[4]; const float* a[4];
  const float* wb[4]; const float* bb[4]; const float* wl;
};

__device__ __forceinline__ unsigned short f2bf(float f) {
  return __bfloat16_as_ushort(__float2bfloat16(f));
}
__device__ __forceinline__ float bflo(unsigned int w) {
  return __uint_as_float(w << 16);
}
__device__ __forceinline__ float bfhi(unsigned int w) {
  return __uint_as_float(w & 0xffff0000u);
}
__device__ __forceinline__ unsigned int pack2(float a, float b) {
  return (unsigned int)f2bf(a) | ((unsigned int)f2bf(b) << 16);
}
__device__ __forceinline__ unsigned int prelu2(unsigned int w, float al) {
  float lo = bflo(w), hi = bfhi(w);
  lo = fmaxf(lo, 0.f) + al * fminf(lo, 0.f);
  hi = fmaxf(hi, 0.f) + al * fminf(hi, 0.f);
  return pack2(lo, hi);
}

// ---- setup: DCT matrices + 81x81 angular Kronecker table ----
__global__ __launch_bounds__(256) void k_setup(float* dctS, float* dctSt,
                                               float* T81, float* T81t) {
  const double PI = 3.14159265358979323846;
  int t = threadIdx.x;
  for (int idx = t; idx < 128 * 128; idx += 256) {
    int k = idx >> 7, i = idx & 127;
    double m = cos(PI * (i + 0.5) * k / 128.0) * sqrt(2.0 / 128.0);
    if (k == 0) m *= (1.0 / sqrt(2.0));
    dctS[k * 128 + i] = (float)m;
    dctSt[i * 128 + k] = (float)m;
  }
  for (int idx = t; idx < 6561; idx += 256) {
    int al = idx / 81, be = idx % 81;
    int Uu = al / 9, Vv = al % 9, uu = be / 9, vv = be % 9;
    double d1 = cos(PI * (uu + 0.5) * Uu / 9.0) * sqrt(2.0 / 9.0);
    if (Uu == 0) d1 *= (1.0 / sqrt(2.0));
    double d2 = cos(PI * (vv + 0.5) * Vv / 9.0) * sqrt(2.0 / 9.0);
    if (Vv == 0) d2 *= (1.0 / sqrt(2.0));
    float tv = (float)(d1 * d2);
    T81[al * 81 + be] = tv;
    T81t[be * 81 + al] = tv;
  }
}

// ---- weight repack into MFMA A-fragment order ----
// Wmf element at ((set*15 + step)*64 + lane)*8 + j  (bf16)
// set: 0..3 = init conv g ; 4..11 = res conv g*2+k
// A[m=lane&15][k=quad*8+j], K-index = 32*i + quad*8 + j -> tap=K>>4 (local,
// 2i+(quad>>1)), cin=K&15. taps per dz padded 9->10 (tap_local 9 => 0 weight).
__global__ __launch_bounds__(256) void k_prep(WPtrs P, unsigned short* Wmf,
                                              float* BiF, float* BbF,
                                              float* AF, float* WlF) {
  int t = blockIdx.x * 256 + threadIdx.x;
  if (t < 92160) {
    int s = t / 7680, r = t % 7680;
    int step = r / 512, r2 = r % 512;
    int lane = r2 >> 3, j = r2 & 7;
    int d = step / 5, i = step % 5;
    int q = lane >> 4, m = lane & 15;
    int tl = 2 * i + (q >> 1);
    int cin = (q & 1) * 8 + j;
    float val = 0.f;
    if (tl <= 8) {
      int ky = tl / 3, kx = tl % 3;
      int tap = d * 9 + ky * 3 + kx;
      if (s < 4) {
        if (cin < 3) val = P.wi[s][(m * 3 + cin) * 27 + tap];
      } else {
        int g = (s - 4) >> 1, k = (s - 4) & 1;
        val = P.wb[g][((k * 16 + m) * 16 + cin) * 27 + tap];
      }
    }
    Wmf[t] = f2bf(val);
  }
  if (t < 64)  BiF[t] = P.bi[t / 16][t % 16];
  if (t < 128) BbF[t] = P.bb[t / 32][t % 32];
  if (t < 8)   AF[t]  = P.a[t / 2][t % 2];
  if (t < 48)  WlF[t] = P.wl[t];
}

// ---- batched 128x128 left/right multiplies (spatial DCT stages) ----
__global__ __launch_bounds__(256) void k_lmul(const float* __restrict__ X,
                                              const float* __restrict__ W,
                                              float* __restrict__ Y) {
  int w = threadIdx.x & 127;
  int ih = threadIdx.x >> 7;
  int s = blockIdx.x;
  int i0 = blockIdx.y * 32 + ih * 16;
  const float* Xs = X + (size_t)s * HW;
  float acc[16];
#pragma unroll
  for (int k = 0; k < 16; k++) acc[k] = 0.f;
  for (int h = 0; h < 128; h++) {
    float xv = Xs[h * 128 + w];
    const float4* wr = (const float4*)(W + h * 128 + i0);
    float4 w0 = wr[0], w1 = wr[1], w2 = wr[2], w3 = wr[3];
    acc[0] += xv * w0.x;  acc[1] += xv * w0.y;  acc[2] += xv * w0.z;  acc[3] += xv * w0.w;
    acc[4] += xv * w1.x;  acc[5] += xv * w1.y;  acc[6] += xv * w1.z;  acc[7] += xv * w1.w;
    acc[8] += xv * w2.x;  acc[9] += xv * w2.y;  acc[10] += xv * w2.z; acc[11] += xv * w2.w;
    acc[12] += xv * w3.x; acc[13] += xv * w3.y; acc[14] += xv * w3.z; acc[15] += xv * w3.w;
  }
  float* Yo = Y + (size_t)s * HW + w;
#pragma unroll
  for (int k = 0; k < 16; k++) Yo[(i0 + k) * 128] = acc[k];
}

__global__ __launch_bounds__(256) void k_rmul(const float* __restrict__ X,
                                              const float* __restrict__ W2,
                                              float* __restrict__ Y) {
  int j = threadIdx.x & 127;
  int jh = threadIdx.x >> 7;
  int s = blockIdx.x;
  int h0 = blockIdx.y * 32 + jh * 16;
  const float* Xs = X + (size_t)s * HW;
  float acc[16];
#pragma unroll
  for (int k = 0; k < 16; k++) acc[k] = 0.f;
  for (int w = 0; w < 128; w++) {
    float wv = W2[w * 128 + j];
#pragma unroll
    for (int k = 0; k < 16; k++) acc[k] += Xs[(h0 + k) * 128 + w] * wv;
  }
  float* Yo = Y + (size_t)s * HW;
#pragma unroll
  for (int k = 0; k < 16; k++) Yo[(h0 + k) * 128 + j] = acc[k];
}

__global__ __launch_bounds__(256) void k_rmul_add(const float* __restrict__ X,
                                                  const float* __restrict__ W2,
                                                  const float* __restrict__ xin,
                                                  float* __restrict__ out) {
  int j = threadIdx.x & 127;
  int jh = threadIdx.x >> 7;
  int s = blockIdx.x;
  int h0 = blockIdx.y * 32 + jh * 16;
  const float* Xs = X + (size_t)s * HW;
  float acc[16];
#pragma unroll
  for (int k = 0; k < 16; k++) acc[k] = 0.f;
  for (int w = 0; w < 128; w++) {
    float wv = W2[w * 128 + j];
#pragma unroll
    for (int k = 0; k < 16; k++) acc[k] += Xs[(h0 + k) * 128 + w] * wv;
  }
#pragma unroll
  for (int k = 0; k < 16; k++) {
    size_t oi = (size_t)s * HW + (h0 + k) * 128 + j;
    out[oi] = acc[k] + xin[oi];
  }
}

// ---- angular DCT forward -> banded, channels-last padded-4 bf16 ----
// xf2b[((p*16384)+hw)*4 + c], c=3 zeroed
__global__ __launch_bounds__(256) void k_ang_fwd(const float* __restrict__ xf1,
                                                 const float* __restrict__ T81,
                                                 unsigned short* __restrict__ xf2b) {
  int idx = blockIdx.x * 256 + threadIdx.x;   // 27*HW total
  int hw = idx & (HW - 1);
  int r = idx >> 14;            // 0..26
  int c = r % 3, og = r / 3;
  float f[81];
#pragma unroll
  for (int b = 0; b < 81; b++) f[b] = xf1[(size_t)(b * 3 + c) * HW + hw];
  for (int a = 0; a < 9; a++) {
    int al = og * 9 + a;
    const float* Tr = T81 + al * 81;
    float acc = 0.f;
#pragma unroll
    for (int b = 0; b < 81; b++) acc += Tr[b] * f[b];
    size_t base = ((size_t)c_pos_uv[al] * HW + hw) * 4;
    xf2b[base + c] = f2bf(acc);
    if (c == 0) xf2b[base + 3] = 0;
  }
}

// ---- angular DCT inverse: banded xrb[p][c][hw] -> xr2[slice][hw] ----
__global__ __launch_bounds__(256) void k_ang_inv(const float* __restrict__ xrb,
                                                 const float* __restrict__ T81t,
                                                 float* __restrict__ xr2) {
  int idx = blockIdx.x * 256 + threadIdx.x;
  int hw = idx & (HW - 1);
  int r = idx >> 14;
  int c = r % 3, og = r / 3;
  float f[81];
#pragma unroll
  for (int al = 0; al < 81; al++)
    f[al] = xrb[((size_t)c_pos_uv[al] * 3 + c) * HW + hw];
  for (int a = 0; a < 9; a++) {
    int be = og * 9 + a;
    const float* Tr = T81t + be * 81;
    float acc = 0.f;
#pragma unroll
    for (int al = 0; al < 81; al++) acc += Tr[al] * f[al];
    xr2[((size_t)be * 3 + c) * HW + hw] = acc;
  }
}

// ---- MFMA implicit-GEMM 3x3x3 conv over one band position ----
// Output tile per block: 4 rows x 128 cols x 16 cout at position p=blockIdx.y.
// LDS slab: one dz slice, rows row0-1..row0+4 (6), cols -1..128 (130, idx+1),
// channels-last bf16 in two 8-cin halves: byte ((row*2+half)*132 + col)*16.
// sel: 0=init (src=xf2b bf16[pix][4], no prelu), 1/2=res k (src=prev raw bf16
// [pix][16], prelu with AF in staging; residual added in epilogue).
__global__ __launch_bounds__(256) void k_conv(const unsigned short* __restrict__ src,
                                              const unsigned short* __restrict__ prevRaw,
                                              const unsigned short* __restrict__ Wmf,
                                              const float* __restrict__ BiF,
                                              const float* __restrict__ BbF,
                                              const float* __restrict__ AF,
                                              int sel,
                                              unsigned short* __restrict__ braw) {
  __shared__ unsigned short s_lds[12672];   // 25344 B
  int p = blockIdx.y;
  int s = c_s_of_p[p], l = c_l_of_p[p];
  int g = c_g_of_s[s], Ls = c_L_of_s[s];
  int row0 = blockIdx.x * 4;
  int t = threadIdx.x;
  int lane = t & 63, wv = t >> 6;
  int q = lane >> 4, n = lane & 15;

  float alpha = 0.f;
  if (sel == 1) alpha = AF[g * 2];
  if (sel == 2) alpha = AF[g * 2 + 1];

  // per-lane B-read offsets (bytes) for the 5 K-steps of a dz phase
  int basel = wv * 4224 + (q & 1) * 2112 + n * 16;
  int off2[5];
#pragma unroll
  for (int i = 0; i < 5; i++) {
    int tl = 2 * i + (q >> 1);
    if (tl > 8) tl = 8;                      // pad tap reads tap8 (zero weight)
    int ky = tl / 3, kx = tl % 3;
    off2[i] = basel + ky * 4224 + kx * 16;
  }

  int setIdx = (sel == 0) ? g : (4 + g * 2 + (sel - 1));
  const char* WsetBase = (const char*)Wmf + (size_t)setIdx * 15 * 1024;

  floatx4 acc[8];
#pragma unroll
  for (int cg = 0; cg < 8; cg++) acc[cg] = (floatx4){0.f, 0.f, 0.f, 0.f};

  for (int d = 0; d < 3; d++) {
    int l2 = l + d - 1;
    if (l2 < 0 || l2 >= Ls) continue;       // block-uniform
    int p2 = p + d - 1;
    __syncthreads();
    // ---- stage slab into LDS ----
    for (int c = t; c < 1560; c += 256) {
      int half = c & 1, cc = c >> 1;
      int col = cc % 130, row = cc / 130;
      int grow = row0 - 1 + row, gcol = col - 1;
      bool v = ((unsigned)grow < 128u) && ((unsigned)gcol < 128u);
      uint4v val = (uint4v){0u, 0u, 0u, 0u};
      if (sel == 0) {
        if (v && half == 0) {
          const unsigned int* sp = (const unsigned int*)(src) +
              ((size_t)p2 * HW + grow * 128 + gcol) * 2;
          val.x = sp[0]; val.y = sp[1];      // [c0c1, c2 0]; rest zero
        }
      } else {
        if (v) {
          const uint4v* sp = (const uint4v*)(src +
              (((size_t)p2 * HW + grow * 128 + gcol) * 16 + half * 8));
          uint4v rv = *sp;
          val.x = prelu2(rv.x, alpha); val.y = prelu2(rv.y, alpha);
          val.z = prelu2(rv.z, alpha); val.w = prelu2(rv.w, alpha);
        }
      }
      *(uint4v*)((char*)s_lds + ((size_t)((row * 2 + half) * 132 + col)) * 16) = val;
    }
    __syncthreads();
    // ---- A fragments for this dz phase ----
    short8 af[5];
#pragma unroll
    for (int i = 0; i < 5; i++)
      af[i] = *(const short8*)(WsetBase + ((d * 5 + i) * 64 + lane) * 16);
    // ---- MFMA over 8 col-groups ----
#pragma unroll
    for (int cg = 0; cg < 8; cg++) {
#pragma unroll
      for (int i = 0; i < 5; i++) {
        short8 b = *(const short8*)((const char*)s_lds + off2[i] + cg * 256);
        acc[cg] = __builtin_amdgcn_mfma_f32_16x16x32_bf16(af[i], b, acc[cg], 0, 0, 0);
      }
    }
  }

  // ---- epilogue: bias (+ residual), pack bf16, coalesced 8B stores ----
  const float* bp = (sel == 0) ? (BiF + g * 16) : (BbF + g * 32 + (sel - 1) * 16);
  float bz[4];
#pragma unroll
  for (int r = 0; r < 4; r++) bz[r] = bp[q * 4 + r];
  int h = row0 + wv;
#pragma unroll
  for (int cg = 0; cg < 8; cg++) {
    size_t pix = (size_t)p * HW + h * 128 + cg * 16 + n;
    float r0 = acc[cg][0] + bz[0], r1 = acc[cg][1] + bz[1];
    float r2 = acc[cg][2] + bz[2], r3 = acc[cg][3] + bz[3];
    if (sel != 0) {
      uint2v pv = *(const uint2v*)(prevRaw + pix * 16 + q * 4);
      r0 += bflo(pv.x); r1 += bfhi(pv.x);
      r2 += bflo(pv.y); r3 += bfhi(pv.y);
    }
    uint2v ov; ov.x = pack2(r0, r1); ov.y = pack2(r2, r3);
    *(uint2v*)(braw + pix * 16 + q * 4) = ov;
  }
}

// ---- epilogue 1x1: xrb[p][c][hw] = sum_n Wl[c][n]*(b0+b2), channels-last in ----
__global__ __launch_bounds__(256) void k_epi(const unsigned short* __restrict__ b0,
                                             const unsigned short* __restrict__ b2,
                                             const float* __restrict__ WlF,
                                             float* __restrict__ xrb) {
  int idx = blockIdx.x * 256 + threadIdx.x;  // 81*HW
  int hw = idx & (HW - 1);
  int p = idx >> 14;
  size_t base = ((size_t)p * HW + hw) * 16;
  uint4v a0 = *(const uint4v*)(b0 + base);
  uint4v a1 = *(const uint4v*)(b0 + base + 8);
  uint4v c0 = *(const uint4v*)(b2 + base);
  uint4v c1 = *(const uint4v*)(b2 + base + 8);
  float v[16];
  v[0] = bflo(a0.x) + bflo(c0.x);  v[1] = bfhi(a0.x) + bfhi(c0.x);
  v[2] = bflo(a0.y) + bflo(c0.y);  v[3] = bfhi(a0.y) + bfhi(c0.y);
  v[4] = bflo(a0.z) + bflo(c0.z);  v[5] = bfhi(a0.z) + bfhi(c0.z);
  v[6] = bflo(a0.w) + bflo(c0.w);  v[7] = bfhi(a0.w) + bfhi(c0.w);
  v[8] = bflo(a1.x) + bflo(c1.x);  v[9] = bfhi(a1.x) + bfhi(c1.x);
  v[10] = bflo(a1.y) + bflo(c1.y); v[11] = bfhi(a1.y) + bfhi(c1.y);
  v[12] = bflo(a1.z) + bflo(c1.z); v[13] = bfhi(a1.z) + bfhi(c1.z);
  v[14] = bflo(a1.w) + bflo(c1.w); v[15] = bfhi(a1.w) + bfhi(c1.w);
  float o0 = 0.f, o1 = 0.f, o2 = 0.f;
#pragma unroll
  for (int k = 0; k < 16; k++) {
    o0 += WlF[k] * v[k]; o1 += WlF[16 + k] * v[k]; o2 += WlF[32 + k] * v[k];
  }
  xrb[((size_t)p * 3 + 0) * HW + hw] = o0;
  xrb[((size_t)p * 3 + 1) * HW + hw] = o1;
  xrb[((size_t)p * 3 + 2) * HW + hw] = o2;
}

extern "C" void kernel_launch(void* const* d_in, const int* in_sizes, int n_in,
                              void* d_out, int out_size, void* d_ws, size_t ws_size,
                              hipStream_t stream) {
  (void)in_sizes; (void)n_in; (void)out_size; (void)ws_size;
  const float* x = (const float*)d_in[0];
  WPtrs P;
  for (int g = 0; g < 4; g++) {
    int b = 1 + g * 5;
    P.wi[g] = (const float*)d_in[b + 0];
    P.bi[g] = (const float*)d_in[b + 1];
    P.a[g]  = (const float*)d_in[b + 2];
    P.wb[g] = (const float*)d_in[b + 3];
    P.bb[g] = (const float*)d_in[b + 4];
  }
  P.wl = (const float*)d_in[21];

  char* base = (char*)d_ws;
  size_t off = 0;
  auto take = [&](size_t bytes) -> char* {
    char* r = base + off;
    off += (bytes + 255) & ~(size_t)255;
    return r;
  };
  float* dctS  = (float*)take(65536);
  float* dctSt = (float*)take(65536);
  float* T81   = (float*)take(26244);
  float* T81t  = (float*)take(26244);
  unsigned short* Wmf = (unsigned short*)take(92160 * 2);
  float* BiF   = (float*)take(256);
  float* BbF   = (float*)take(512);
  float* AF    = (float*)take(32);
  float* WlF   = (float*)take(192);
  // fp32 slice regions (time-shared)
  float* R1 = (float*)take((size_t)NSLICE * HW * 4);   // lmul out | ang_inv out
  float* R2 = (float*)take((size_t)NSLICE * HW * 4);   // rmul out | lmul2 out
  float* R3 = (float*)take((size_t)NSLICE * HW * 4);   // xf2b (bf16) | xrb (f32)
  unsigned short* braw0 = (unsigned short*)take((size_t)81 * 16 * HW * 2);
  unsigned short* braw1 = (unsigned short*)take((size_t)81 * 16 * HW * 2);
  unsigned short* braw2 = (unsigned short*)take((size_t)81 * 16 * HW * 2);
  unsigned short* xf2b = (unsigned short*)R3;          // 10.6 MB < 15.9 MB
  float* xrb = R3;

  k_setup<<<1, 256, 0, stream>>>(dctS, dctSt, T81, T81t);
  k_prep<<<360, 256, 0, stream>>>(P, Wmf, BiF, BbF, AF, WlF);
  // forward spatial DCT
  k_lmul<<<dim3(243, 4), 256, 0, stream>>>(x, dctSt, R1);
  k_rmul<<<dim3(243, 4), 256, 0, stream>>>(R1, dctSt, R2);
  // forward angular DCT + band gather -> channels-last bf16
  k_ang_fwd<<<1728, 256, 0, stream>>>(R2, T81, xf2b);
  // branch convs (MFMA implicit GEMM)
  k_conv<<<dim3(32, 81), 256, 0, stream>>>(xf2b, nullptr, Wmf, BiF, BbF, AF, 0, braw0);
  k_conv<<<dim3(32, 81), 256, 0, stream>>>(braw0, braw0, Wmf, BiF, BbF, AF, 1, braw1);
  k_conv<<<dim3(32, 81), 256, 0, stream>>>(braw1, braw1, Wmf, BiF, BbF, AF, 2, braw2);
  // (y0 + y2) then folded 1x1 conv -> xrb
  k_epi<<<5184, 256, 0, stream>>>(braw0, braw2, WlF, xrb);
  // inverse angular DCT
  k_ang_inv<<<1728, 256, 0, stream>>>(xrb, T81t, R1);
  // inverse spatial DCT + residual add
  k_lmul<<<dim3(243, 4), 256, 0, stream>>>(R1, dctS, R2);
  k_rmul_add<<<dim3(243, 4), 256, 0, stream>>>(R2, dctS, x, (float*)d_out);
}

// Round 4
// 412.965 us; speedup vs baseline: 3.6703x; 1.5970x over previous
//
#include <hip/hip_runtime.h>
#include <hip/hip_bf16.h>
#include <math.h>

typedef __hip_bfloat16 bf16;
typedef __attribute__((ext_vector_type(8))) short short8;
typedef __attribute__((ext_vector_type(4))) float floatx4;
typedef __attribute__((ext_vector_type(4))) unsigned int uint4v;
typedef __attribute__((ext_vector_type(2))) unsigned int uint2v;

#define HW 16384          // 128*128
#define NSLICE 243        // 9*9*3

// ---- band tables (anti-diagonals of 9x9 grid) ----
__constant__ int c_s_of_p[81] = {
  0, 1,1, 2,2,2, 3,3,3,3, 4,4,4,4,4, 5,5,5,5,5,5, 6,6,6,6,6,6,6,
  7,7,7,7,7,7,7,7, 8,8,8,8,8,8,8,8,8, 9,9,9,9,9,9,9,9,
  10,10,10,10,10,10,10, 11,11,11,11,11,11, 12,12,12,12,12,
  13,13,13,13, 14,14,14, 15,15, 16};
__constant__ int c_l_of_p[81] = {
  0, 0,1, 0,1,2, 0,1,2,3, 0,1,2,3,4, 0,1,2,3,4,5, 0,1,2,3,4,5,6,
  0,1,2,3,4,5,6,7, 0,1,2,3,4,5,6,7,8, 0,1,2,3,4,5,6,7,
  0,1,2,3,4,5,6, 0,1,2,3,4,5, 0,1,2,3,4, 0,1,2,3, 0,1,2, 0,1, 0};
__constant__ int c_L_of_s[17] = {1,2,3,4,5,6,7,8,9,8,7,6,5,4,3,2,1};
__constant__ int c_g_of_s[17] = {0,1,1,2,2,2,2,2,2,3,3,3,3,3,3,3,3};
__constant__ int c_pos_uv[81] = {
  0,1,3,6,10,15,21,28,36,
  2,4,7,11,16,22,29,37,45,
  5,8,12,17,23,30,38,46,53,
  9,13,18,24,31,39,47,54,60,
  14,19,25,32,40,48,55,61,66,
  20,26,33,41,49,56,62,67,71,
  27,34,42,50,57,63,68,72,75,
  35,43,51,58,64,69,73,76,78,
  44,52,59,65,70,74,77,79,80};

struct WPtrs {
  const float* wi[4]; const float* bi[4]; const float* a[4];
  const float* wb[4]; const float* bb[4]; const float* wl;
};

__device__ __forceinline__ unsigned short f2bf(float f) {
  return __bfloat16_as_ushort(__float2bfloat16(f));
}
__device__ __forceinline__ float bflo(unsigned int w) {
  return __uint_as_float(w << 16);
}
__device__ __forceinline__ float bfhi(unsigned int w) {
  return __uint_as_float(w & 0xffff0000u);
}
__device__ __forceinline__ unsigned int pack2(float a, float b) {
  return (unsigned int)f2bf(a) | ((unsigned int)f2bf(b) << 16);
}
__device__ __forceinline__ unsigned int prelu2(unsigned int w, float al) {
  float lo = bflo(w), hi = bfhi(w);
  lo = fmaxf(lo, 0.f) + al * fminf(lo, 0.f);
  hi = fmaxf(hi, 0.f) + al * fminf(hi, 0.f);
  return pack2(lo, hi);
}
// split fp32 into bf16 hi (truncate) + bf16 lo (RNE of remainder): ~2^-17 rel
__device__ __forceinline__ void bfsplit(float v, unsigned short& hi, unsigned short& lo) {
  unsigned int bits = __float_as_uint(v);
  hi = (unsigned short)(bits >> 16);
  lo = f2bf(v - __uint_as_float(bits & 0xffff0000u));
}

// ---- setup: angular Kronecker table + spatial-DCT MFMA fragment tables ----
// Fragment tables (bf16 hi/lo): entry e = ((tile*4+ks)*64+lane)*8+jj
//   row = tile*16+(lane&15), colk = ks*32+(lane>>4)*8+jj
//   TabF = Ds[row][colk]  (fwd: stage1-B and stage2-A)
//   TabI = Ds[colk][row]  (inv: stage1-B and stage2-A)
__global__ __launch_bounds__(256) void k_setup(float* T81, float* T81t,
                                               unsigned short* TFhi, unsigned short* TFlo,
                                               unsigned short* TIhi, unsigned short* TIlo) {
  const double PI = 3.14159265358979323846;
  int t = blockIdx.x * 256 + threadIdx.x;
  if (t < 6561) {
    int al = t / 81, be = t % 81;
    int Uu = al / 9, Vv = al % 9, uu = be / 9, vv = be % 9;
    double d1 = cos(PI * (uu + 0.5) * Uu / 9.0) * sqrt(2.0 / 9.0);
    if (Uu == 0) d1 *= (1.0 / sqrt(2.0));
    double d2 = cos(PI * (vv + 0.5) * Vv / 9.0) * sqrt(2.0 / 9.0);
    if (Vv == 0) d2 *= (1.0 / sqrt(2.0));
    float tv = (float)(d1 * d2);
    T81[al * 81 + be] = tv;
    T81t[be * 81 + al] = tv;
  }
  if (t < 16384) {
    int jj = t & 7, lane = (t >> 3) & 63, ks = (t >> 9) & 3, tile = t >> 11;
    int row = tile * 16 + (lane & 15);
    int colk = ks * 32 + (lane >> 4) * 8 + jj;
    double vF = cos(PI * (colk + 0.5) * row / 128.0) * sqrt(2.0 / 128.0);
    if (row == 0) vF *= (1.0 / sqrt(2.0));
    double vI = cos(PI * (row + 0.5) * colk / 128.0) * sqrt(2.0 / 128.0);
    if (colk == 0) vI *= (1.0 / sqrt(2.0));
    unsigned short h, l;
    bfsplit((float)vF, h, l); TFhi[t] = h; TFlo[t] = l;
    bfsplit((float)vI, h, l); TIhi[t] = h; TIlo[t] = l;
  }
}

// ---- conv weight repack into MFMA A-fragment order (unchanged) ----
__global__ __launch_bounds__(256) void k_prep(WPtrs P, unsigned short* Wmf,
                                              float* BiF, float* BbF,
                                              float* AF, float* WlF) {
  int t = blockIdx.x * 256 + threadIdx.x;
  if (t < 92160) {
    int s = t / 7680, r = t % 7680;
    int step = r / 512, r2 = r % 512;
    int lane = r2 >> 3, j = r2 & 7;
    int d = step / 5, i = step % 5;
    int q = lane >> 4, m = lane & 15;
    int tl = 2 * i + (q >> 1);
    int cin = (q & 1) * 8 + j;
    float val = 0.f;
    if (tl <= 8) {
      int ky = tl / 3, kx = tl % 3;
      int tap = d * 9 + ky * 3 + kx;
      if (s < 4) {
        if (cin < 3) val = P.wi[s][(m * 3 + cin) * 27 + tap];
      } else {
        int g = (s - 4) >> 1, k = (s - 4) & 1;
        val = P.wb[g][((k * 16 + m) * 16 + cin) * 27 + tap];
      }
    }
    Wmf[t] = f2bf(val);
  }
  if (t < 64)  BiF[t] = P.bi[t / 16][t % 16];
  if (t < 128) BbF[t] = P.bb[t / 32][t % 32];
  if (t < 8)   AF[t]  = P.a[t / 2][t % 2];
  if (t < 48)  WlF[t] = P.wl[t];
}

// ---- fused spatial DCT: Y = Dop * X * Dop^T per 128x128 slice ----
// tab = TabF (fwd, Dop=Ds) or TabI (inv, Dop=Ds^T). Split-bf16 MFMA, 3 terms.
// Stage1: T = X * Dop^T  (A=X rows from global, B=tab)
// Stage2: Y = Dop * T    (A=tab, B=T^T staged hi/lo in LDS, pad 136)
__global__ __launch_bounds__(256) void k_dct2(const float* __restrict__ X,
                                              const unsigned short* __restrict__ tabhi,
                                              const unsigned short* __restrict__ tablo,
                                              const float* __restrict__ xres,
                                              float* __restrict__ Y) {
  __shared__ unsigned short sThi[128 * 136];
  __shared__ unsigned short sTlo[128 * 136];
  int s = blockIdx.x;
  int t = threadIdx.x;
  int lane = t & 63, wv = t >> 6;
  int q = lane >> 4, n16 = lane & 15;
  const float* Xs = X + (size_t)s * HW;

  floatx4 acc[2][8];
#pragma unroll
  for (int mt = 0; mt < 2; mt++)
#pragma unroll
    for (int nt = 0; nt < 8; nt++) acc[mt][nt] = (floatx4){0.f, 0.f, 0.f, 0.f};

  // ---- stage 1 ----
#pragma unroll
  for (int ks = 0; ks < 4; ks++) {
    short8 ahi[2], alo[2];
#pragma unroll
    for (int mt = 0; mt < 2; mt++) {
      const float* xp = Xs + (wv * 32 + mt * 16 + n16) * 128 + ks * 32 + q * 8;
      float4 a = *(const float4*)xp;
      float4 b = *(const float4*)(xp + 4);
      union { short8 v; unsigned short u[8]; } H, L;
      float xv[8] = {a.x, a.y, a.z, a.w, b.x, b.y, b.z, b.w};
#pragma unroll
      for (int j = 0; j < 8; j++) bfsplit(xv[j], H.u[j], L.u[j]);
      ahi[mt] = H.v; alo[mt] = L.v;
    }
#pragma unroll
    for (int nt = 0; nt < 8; nt++) {
      int e = nt * 2048 + ks * 512 + lane * 8;
      short8 bh = *(const short8*)(tabhi + e);
      short8 bl = *(const short8*)(tablo + e);
#pragma unroll
      for (int mt = 0; mt < 2; mt++) {
        acc[mt][nt] = __builtin_amdgcn_mfma_f32_16x16x32_bf16(ahi[mt], bl, acc[mt][nt], 0, 0, 0);
        acc[mt][nt] = __builtin_amdgcn_mfma_f32_16x16x32_bf16(alo[mt], bh, acc[mt][nt], 0, 0, 0);
        acc[mt][nt] = __builtin_amdgcn_mfma_f32_16x16x32_bf16(ahi[mt], bh, acc[mt][nt], 0, 0, 0);
      }
    }
  }

  // ---- store T transposed into LDS (hi/lo planes, row pad 136) ----
#pragma unroll
  for (int mt = 0; mt < 2; mt++)
#pragma unroll
    for (int nt = 0; nt < 8; nt++) {
      int col = nt * 16 + n16;
      int rowb = wv * 32 + mt * 16 + q * 4;
#pragma unroll
      for (int rp = 0; rp < 4; rp += 2) {
        unsigned short h0, l0, h1, l1;
        bfsplit(acc[mt][nt][rp], h0, l0);
        bfsplit(acc[mt][nt][rp + 1], h1, l1);
        int widx = (col * 136 + rowb + rp) >> 1;   // ushort offset even -> uint idx
        ((unsigned int*)sThi)[widx] = (unsigned int)h0 | ((unsigned int)h1 << 16);
        ((unsigned int*)sTlo)[widx] = (unsigned int)l0 | ((unsigned int)l1 << 16);
      }
    }
  __syncthreads();

  // ---- stage 2 ----
#pragma unroll
  for (int mt = 0; mt < 2; mt++)
#pragma unroll
    for (int nt = 0; nt < 8; nt++) acc[mt][nt] = (floatx4){0.f, 0.f, 0.f, 0.f};

#pragma unroll
  for (int ks = 0; ks < 4; ks++) {
    short8 ahi[2], alo[2];
#pragma unroll
    for (int mt = 0; mt < 2; mt++) {
      int e = (wv * 2 + mt) * 2048 + ks * 512 + lane * 8;
      ahi[mt] = *(const short8*)(tabhi + e);
      alo[mt] = *(const short8*)(tablo + e);
    }
#pragma unroll
    for (int nt = 0; nt < 8; nt++) {
      int off = (nt * 16 + n16) * 136 + ks * 32 + q * 8;
      short8 bh = *(const short8*)(sThi + off);
      short8 bl = *(const short8*)(sTlo + off);
#pragma unroll
      for (int mt = 0; mt < 2; mt++) {
        acc[mt][nt] = __builtin_amdgcn_mfma_f32_16x16x32_bf16(ahi[mt], bl, acc[mt][nt], 0, 0, 0);
        acc[mt][nt] = __builtin_amdgcn_mfma_f32_16x16x32_bf16(alo[mt], bh, acc[mt][nt], 0, 0, 0);
        acc[mt][nt] = __builtin_amdgcn_mfma_f32_16x16x32_bf16(ahi[mt], bh, acc[mt][nt], 0, 0, 0);
      }
    }
  }

  // ---- epilogue: optional residual add, fp32 store ----
#pragma unroll
  for (int mt = 0; mt < 2; mt++)
#pragma unroll
    for (int nt = 0; nt < 8; nt++) {
      int row0 = wv * 32 + mt * 16 + q * 4;
      int col = nt * 16 + n16;
#pragma unroll
      for (int r = 0; r < 4; r++) {
        size_t oi = (size_t)s * HW + (size_t)(row0 + r) * 128 + col;
        float v = acc[mt][nt][r];
        if (xres) v += xres[oi];
        Y[oi] = v;
      }
    }
}

// ---- angular DCT forward -> banded, channels-last padded-4 bf16 ----
__global__ __launch_bounds__(256) void k_ang_fwd(const float* __restrict__ xf1,
                                                 const float* __restrict__ T81,
                                                 unsigned short* __restrict__ xf2b) {
  int idx = blockIdx.x * 256 + threadIdx.x;   // 27*HW total
  int hw = idx & (HW - 1);
  int r = idx >> 14;            // 0..26
  int c = r % 3, og = r / 3;
  float f[81];
#pragma unroll
  for (int b = 0; b < 81; b++) f[b] = xf1[(size_t)(b * 3 + c) * HW + hw];
  for (int a = 0; a < 9; a++) {
    int al = og * 9 + a;
    const float* Tr = T81 + al * 81;
    float acc = 0.f;
#pragma unroll
    for (int b = 0; b < 81; b++) acc += Tr[b] * f[b];
    size_t base = ((size_t)c_pos_uv[al] * HW + hw) * 4;
    xf2b[base + c] = f2bf(acc);
    if (c == 0) xf2b[base + 3] = 0;
  }
}

// ---- angular DCT inverse: banded xrb[p][c][hw] -> xr2[slice][hw] ----
__global__ __launch_bounds__(256) void k_ang_inv(const float* __restrict__ xrb,
                                                 const float* __restrict__ T81t,
                                                 float* __restrict__ xr2) {
  int idx = blockIdx.x * 256 + threadIdx.x;
  int hw = idx & (HW - 1);
  int r = idx >> 14;
  int c = r % 3, og = r / 3;
  float f[81];
#pragma unroll
  for (int al = 0; al < 81; al++)
    f[al] = xrb[((size_t)c_pos_uv[al] * 3 + c) * HW + hw];
  for (int a = 0; a < 9; a++) {
    int be = og * 9 + a;
    const float* Tr = T81t + be * 81;
    float acc = 0.f;
#pragma unroll
    for (int al = 0; al < 81; al++) acc += Tr[al] * f[al];
    xr2[((size_t)be * 3 + c) * HW + hw] = acc;
  }
}

// ---- MFMA implicit-GEMM 3x3x3 conv over one band position (unchanged) ----
__global__ __launch_bounds__(256) void k_conv(const unsigned short* __restrict__ src,
                                              const unsigned short* __restrict__ prevRaw,
                                              const unsigned short* __restrict__ Wmf,
                                              const float* __restrict__ BiF,
                                              const float* __restrict__ BbF,
                                              const float* __restrict__ AF,
                                              int sel,
                                              unsigned short* __restrict__ braw) {
  __shared__ unsigned short s_lds[12672];   // 25344 B
  int p = blockIdx.y;
  int s = c_s_of_p[p], l = c_l_of_p[p];
  int g = c_g_of_s[s], Ls = c_L_of_s[s];
  int row0 = blockIdx.x * 4;
  int t = threadIdx.x;
  int lane = t & 63, wv = t >> 6;
  int q = lane >> 4, n = lane & 15;

  float alpha = 0.f;
  if (sel == 1) alpha = AF[g * 2];
  if (sel == 2) alpha = AF[g * 2 + 1];

  int basel = wv * 4224 + (q & 1) * 2112 + n * 16;
  int off2[5];
#pragma unroll
  for (int i = 0; i < 5; i++) {
    int tl = 2 * i + (q >> 1);
    if (tl > 8) tl = 8;
    int ky = tl / 3, kx = tl % 3;
    off2[i] = basel + ky * 4224 + kx * 16;
  }

  int setIdx = (sel == 0) ? g : (4 + g * 2 + (sel - 1));
  const char* WsetBase = (const char*)Wmf + (size_t)setIdx * 15 * 1024;

  floatx4 acc[8];
#pragma unroll
  for (int cg = 0; cg < 8; cg++) acc[cg] = (floatx4){0.f, 0.f, 0.f, 0.f};

  for (int d = 0; d < 3; d++) {
    int l2 = l + d - 1;
    if (l2 < 0 || l2 >= Ls) continue;
    int p2 = p + d - 1;
    __syncthreads();
    for (int c = t; c < 1560; c += 256) {
      int half = c & 1, cc = c >> 1;
      int col = cc % 130, row = cc / 130;
      int grow = row0 - 1 + row, gcol = col - 1;
      bool v = ((unsigned)grow < 128u) && ((unsigned)gcol < 128u);
      uint4v val = (uint4v){0u, 0u, 0u, 0u};
      if (sel == 0) {
        if (v && half == 0) {
          const unsigned int* sp = (const unsigned int*)(src) +
              ((size_t)p2 * HW + grow * 128 + gcol) * 2;
          val.x = sp[0]; val.y = sp[1];
        }
      } else {
        if (v) {
          const uint4v* sp = (const uint4v*)(src +
              (((size_t)p2 * HW + grow * 128 + gcol) * 16 + half * 8));
          uint4v rv = *sp;
          val.x = prelu2(rv.x, alpha); val.y = prelu2(rv.y, alpha);
          val.z = prelu2(rv.z, alpha); val.w = prelu2(rv.w, alpha);
        }
      }
      *(uint4v*)((char*)s_lds + ((size_t)((row * 2 + half) * 132 + col)) * 16) = val;
    }
    __syncthreads();
    short8 af[5];
#pragma unroll
    for (int i = 0; i < 5; i++)
      af[i] = *(const short8*)(WsetBase + ((d * 5 + i) * 64 + lane) * 16);
#pragma unroll
    for (int cg = 0; cg < 8; cg++) {
#pragma unroll
      for (int i = 0; i < 5; i++) {
        short8 b = *(const short8*)((const char*)s_lds + off2[i] + cg * 256);
        acc[cg] = __builtin_amdgcn_mfma_f32_16x16x32_bf16(af[i], b, acc[cg], 0, 0, 0);
      }
    }
  }

  const float* bp = (sel == 0) ? (BiF + g * 16) : (BbF + g * 32 + (sel - 1) * 16);
  float bz[4];
#pragma unroll
  for (int r = 0; r < 4; r++) bz[r] = bp[q * 4 + r];
  int h = row0 + wv;
#pragma unroll
  for (int cg = 0; cg < 8; cg++) {
    size_t pix = (size_t)p * HW + h * 128 + cg * 16 + n;
    float r0 = acc[cg][0] + bz[0], r1 = acc[cg][1] + bz[1];
    float r2 = acc[cg][2] + bz[2], r3 = acc[cg][3] + bz[3];
    if (sel != 0) {
      uint2v pv = *(const uint2v*)(prevRaw + pix * 16 + q * 4);
      r0 += bflo(pv.x); r1 += bfhi(pv.x);
      r2 += bflo(pv.y); r3 += bfhi(pv.y);
    }
    uint2v ov; ov.x = pack2(r0, r1); ov.y = pack2(r2, r3);
    *(uint2v*)(braw + pix * 16 + q * 4) = ov;
  }
}

// ---- epilogue 1x1: xrb[p][c][hw] = sum_n Wl[c][n]*(b0+b2), channels-last in ----
__global__ __launch_bounds__(256) void k_epi(const unsigned short* __restrict__ b0,
                                             const unsigned short* __restrict__ b2,
                                             const float* __restrict__ WlF,
                                             float* __restrict__ xrb) {
  int idx = blockIdx.x * 256 + threadIdx.x;  // 81*HW
  int hw = idx & (HW - 1);
  int p = idx >> 14;
  size_t base = ((size_t)p * HW + hw) * 16;
  uint4v a0 = *(const uint4v*)(b0 + base);
  uint4v a1 = *(const uint4v*)(b0 + base + 8);
  uint4v c0 = *(const uint4v*)(b2 + base);
  uint4v c1 = *(const uint4v*)(b2 + base + 8);
  float v[16];
  v[0] = bflo(a0.x) + bflo(c0.x);  v[1] = bfhi(a0.x) + bfhi(c0.x);
  v[2] = bflo(a0.y) + bflo(c0.y);  v[3] = bfhi(a0.y) + bfhi(c0.y);
  v[4] = bflo(a0.z) + bflo(c0.z);  v[5] = bfhi(a0.z) + bfhi(c0.z);
  v[6] = bflo(a0.w) + bflo(c0.w);  v[7] = bfhi(a0.w) + bfhi(c0.w);
  v[8] = bflo(a1.x) + bflo(c1.x);  v[9] = bfhi(a1.x) + bfhi(c1.x);
  v[10] = bflo(a1.y) + bflo(c1.y); v[11] = bfhi(a1.y) + bfhi(c1.y);
  v[12] = bflo(a1.z) + bflo(c1.z); v[13] = bfhi(a1.z) + bfhi(c1.z);
  v[14] = bflo(a1.w) + bflo(c1.w); v[15] = bfhi(a1.w) + bfhi(c1.w);
  float o0 = 0.f, o1 = 0.f, o2 = 0.f;
#pragma unroll
  for (int k = 0; k < 16; k++) {
    o0 += WlF[k] * v[k]; o1 += WlF[16 + k] * v[k]; o2 += WlF[32 + k] * v[k];
  }
  xrb[((size_t)p * 3 + 0) * HW + hw] = o0;
  xrb[((size_t)p * 3 + 1) * HW + hw] = o1;
  xrb[((size_t)p * 3 + 2) * HW + hw] = o2;
}

extern "C" void kernel_launch(void* const* d_in, const int* in_sizes, int n_in,
                              void* d_out, int out_size, void* d_ws, size_t ws_size,
                              hipStream_t stream) {
  (void)in_sizes; (void)n_in; (void)out_size; (void)ws_size;
  const float* x = (const float*)d_in[0];
  WPtrs P;
  for (int g = 0; g < 4; g++) {
    int b = 1 + g * 5;
    P.wi[g] = (const float*)d_in[b + 0];
    P.bi[g] = (const float*)d_in[b + 1];
    P.a[g]  = (const float*)d_in[b + 2];
    P.wb[g] = (const float*)d_in[b + 3];
    P.bb[g] = (const float*)d_in[b + 4];
  }
  P.wl = (const float*)d_in[21];

  char* base = (char*)d_ws;
  size_t off = 0;
  auto take = [&](size_t bytes) -> char* {
    char* r = base + off;
    off += (bytes + 255) & ~(size_t)255;
    return r;
  };
  float* T81   = (float*)take(26244);
  float* T81t  = (float*)take(26244);
  unsigned short* TFhi = (unsigned short*)take(16384 * 2);
  unsigned short* TFlo = (unsigned short*)take(16384 * 2);
  unsigned short* TIhi = (unsigned short*)take(16384 * 2);
  unsigned short* TIlo = (unsigned short*)take(16384 * 2);
  unsigned short* Wmf = (unsigned short*)take(92160 * 2);
  float* BiF   = (float*)take(256);
  float* BbF   = (float*)take(512);
  float* AF    = (float*)take(32);
  float* WlF   = (float*)take(192);
  float* R1 = (float*)take((size_t)NSLICE * HW * 4);   // dct2 fwd out | ang_inv out
  float* R3 = (float*)take((size_t)NSLICE * HW * 4);   // xf2b (bf16) | xrb (f32)
  unsigned short* braw0 = (unsigned short*)take((size_t)81 * 16 * HW * 2);
  unsigned short* braw1 = (unsigned short*)take((size_t)81 * 16 * HW * 2);
  unsigned short* braw2 = (unsigned short*)take((size_t)81 * 16 * HW * 2);
  unsigned short* xf2b = (unsigned short*)R3;          // 10.6 MB < 15.9 MB
  float* xrb = R3;

  k_setup<<<64, 256, 0, stream>>>(T81, T81t, TFhi, TFlo, TIhi, TIlo);
  k_prep<<<360, 256, 0, stream>>>(P, Wmf, BiF, BbF, AF, WlF);
  // fused forward spatial DCT (per-slice MFMA split-bf16)
  k_dct2<<<243, 256, 0, stream>>>(x, TFhi, TFlo, nullptr, R1);
  // forward angular DCT + band gather -> channels-last bf16
  k_ang_fwd<<<1728, 256, 0, stream>>>(R1, T81, xf2b);
  // branch convs (MFMA implicit GEMM)
  k_conv<<<dim3(32, 81), 256, 0, stream>>>(xf2b, nullptr, Wmf, BiF, BbF, AF, 0, braw0);
  k_conv<<<dim3(32, 81), 256, 0, stream>>>(braw0, braw0, Wmf, BiF, BbF, AF, 1, braw1);
  k_conv<<<dim3(32, 81), 256, 0, stream>>>(braw1, braw1, Wmf, BiF, BbF, AF, 2, braw2);
  // (y0 + y2) then folded 1x1 conv -> xrb
  k_epi<<<5184, 256, 0, stream>>>(braw0, braw2, WlF, xrb);
  // inverse angular DCT
  k_ang_inv<<<1728, 256, 0, stream>>>(xrb, T81t, R1);
  // fused inverse spatial DCT + residual add
  k_dct2<<<243, 256, 0, stream>>>(R1, TIhi, TIlo, x, (float*)d_out);
}

// Round 5
// 317.327 us; speedup vs baseline: 4.7764x; 1.3014x over previous
//
#include <hip/hip_runtime.h>
#include <hip/hip_bf16.h>
#include <math.h>

typedef __hip_bfloat16 bf16;
typedef __attribute__((ext_vector_type(8))) short short8;
typedef __attribute__((ext_vector_type(4))) float floatx4;
typedef __attribute__((ext_vector_type(4))) unsigned int uint4v;
typedef __attribute__((ext_vector_type(2))) unsigned int uint2v;

#define HW 16384          // 128*128
#define NSLICE 243        // 9*9*3

// ---- band tables (anti-diagonals of 9x9 grid) ----
__constant__ int c_s_of_p[81] = {
  0, 1,1, 2,2,2, 3,3,3,3, 4,4,4,4,4, 5,5,5,5,5,5, 6,6,6,6,6,6,6,
  7,7,7,7,7,7,7,7, 8,8,8,8,8,8,8,8,8, 9,9,9,9,9,9,9,9,
  10,10,10,10,10,10,10, 11,11,11,11,11,11, 12,12,12,12,12,
  13,13,13,13, 14,14,14, 15,15, 16};
__constant__ int c_l_of_p[81] = {
  0, 0,1, 0,1,2, 0,1,2,3, 0,1,2,3,4, 0,1,2,3,4,5, 0,1,2,3,4,5,6,
  0,1,2,3,4,5,6,7, 0,1,2,3,4,5,6,7,8, 0,1,2,3,4,5,6,7,
  0,1,2,3,4,5,6, 0,1,2,3,4,5, 0,1,2,3,4, 0,1,2,3, 0,1,2, 0,1, 0};
__constant__ int c_L_of_s[17] = {1,2,3,4,5,6,7,8,9,8,7,6,5,4,3,2,1};
__constant__ int c_g_of_s[17] = {0,1,1,2,2,2,2,2,2,3,3,3,3,3,3,3,3};
__constant__ int c_pos_uv[81] = {
  0,1,3,6,10,15,21,28,36,
  2,4,7,11,16,22,29,37,45,
  5,8,12,17,23,30,38,46,53,
  9,13,18,24,31,39,47,54,60,
  14,19,25,32,40,48,55,61,66,
  20,26,33,41,49,56,62,67,71,
  27,34,42,50,57,63,68,72,75,
  35,43,51,58,64,69,73,76,78,
  44,52,59,65,70,74,77,79,80};

struct WPtrs {
  const float* wi[4]; const float* bi[4]; const float* a[4];
  const float* wb[4]; const float* bb[4]; const float* wl;
};

__device__ __forceinline__ unsigned short f2bf(float f) {
  return __bfloat16_as_ushort(__float2bfloat16(f));
}
__device__ __forceinline__ float bflo(unsigned int w) {
  return __uint_as_float(w << 16);
}
__device__ __forceinline__ float bfhi(unsigned int w) {
  return __uint_as_float(w & 0xffff0000u);
}
__device__ __forceinline__ unsigned int pack2(float a, float b) {
  return (unsigned int)f2bf(a) | ((unsigned int)f2bf(b) << 16);
}
// inverse PReLU: raw = v>=0 ? v : v*invA  (exact for alpha = power of two)
__device__ __forceinline__ float invprelu(float v, float invA) {
  return (v >= 0.f) ? v : v * invA;
}
// split fp32 into bf16 hi (truncate) + bf16 lo (RNE of remainder): ~2^-17 rel
__device__ __forceinline__ void bfsplit(float v, unsigned short& hi, unsigned short& lo) {
  unsigned int bits = __float_as_uint(v);
  hi = (unsigned short)(bits >> 16);
  lo = f2bf(v - __uint_as_float(bits & 0xffff0000u));
}

// ---- setup: 9-point angular DCT matrix + spatial-DCT MFMA fragment tables ----
__global__ __launch_bounds__(256) void k_setup(float* DaF,
                                               unsigned short* TFhi, unsigned short* TFlo,
                                               unsigned short* TIhi, unsigned short* TIlo) {
  const double PI = 3.14159265358979323846;
  int t = blockIdx.x * 256 + threadIdx.x;
  if (t < 81) {   // Da[U][u]
    int U = t / 9, u = t % 9;
    double d = cos(PI * (u + 0.5) * U / 9.0) * sqrt(2.0 / 9.0);
    if (U == 0) d *= (1.0 / sqrt(2.0));
    DaF[t] = (float)d;
  }
  if (t < 16384) {
    int jj = t & 7, lane = (t >> 3) & 63, ks = (t >> 9) & 3, tile = t >> 11;
    int row = tile * 16 + (lane & 15);
    int colk = ks * 32 + (lane >> 4) * 8 + jj;
    double vF = cos(PI * (colk + 0.5) * row / 128.0) * sqrt(2.0 / 128.0);
    if (row == 0) vF *= (1.0 / sqrt(2.0));
    double vI = cos(PI * (row + 0.5) * colk / 128.0) * sqrt(2.0 / 128.0);
    if (colk == 0) vI *= (1.0 / sqrt(2.0));
    unsigned short h, l;
    bfsplit((float)vF, h, l); TFhi[t] = h; TFlo[t] = l;
    bfsplit((float)vI, h, l); TIhi[t] = h; TIlo[t] = l;
  }
}

// ---- conv weight repack into MFMA A-fragment order (unchanged) ----
__global__ __launch_bounds__(256) void k_prep(WPtrs P, unsigned short* Wmf,
                                              float* BiF, float* BbF,
                                              float* AF, float* WlF) {
  int t = blockIdx.x * 256 + threadIdx.x;
  if (t < 92160) {
    int s = t / 7680, r = t % 7680;
    int step = r / 512, r2 = r % 512;
    int lane = r2 >> 3, j = r2 & 7;
    int d = step / 5, i = step % 5;
    int q = lane >> 4, m = lane & 15;
    int tl = 2 * i + (q >> 1);
    int cin = (q & 1) * 8 + j;
    float val = 0.f;
    if (tl <= 8) {
      int ky = tl / 3, kx = tl % 3;
      int tap = d * 9 + ky * 3 + kx;
      if (s < 4) {
        if (cin < 3) val = P.wi[s][(m * 3 + cin) * 27 + tap];
      } else {
        int g = (s - 4) >> 1, k = (s - 4) & 1;
        val = P.wb[g][((k * 16 + m) * 16 + cin) * 27 + tap];
      }
    }
    Wmf[t] = f2bf(val);
  }
  if (t < 64)  BiF[t] = P.bi[t / 16][t % 16];
  if (t < 128) BbF[t] = P.bb[t / 32][t % 32];
  if (t < 8)   AF[t]  = P.a[t / 2][t % 2];
  if (t < 48)  WlF[t] = P.wl[t];
}

// ---- fused spatial DCT: Y = Dop * X * Dop^T per 128x128 slice (unchanged) ----
__global__ __launch_bounds__(256) void k_dct2(const float* __restrict__ X,
                                              const unsigned short* __restrict__ tabhi,
                                              const unsigned short* __restrict__ tablo,
                                              const float* __restrict__ xres,
                                              float* __restrict__ Y) {
  __shared__ unsigned short sThi[128 * 136];
  __shared__ unsigned short sTlo[128 * 136];
  int s = blockIdx.x;
  int t = threadIdx.x;
  int lane = t & 63, wv = t >> 6;
  int q = lane >> 4, n16 = lane & 15;
  const float* Xs = X + (size_t)s * HW;

  floatx4 acc[2][8];
#pragma unroll
  for (int mt = 0; mt < 2; mt++)
#pragma unroll
    for (int nt = 0; nt < 8; nt++) acc[mt][nt] = (floatx4){0.f, 0.f, 0.f, 0.f};

#pragma unroll
  for (int ks = 0; ks < 4; ks++) {
    short8 ahi[2], alo[2];
#pragma unroll
    for (int mt = 0; mt < 2; mt++) {
      const float* xp = Xs + (wv * 32 + mt * 16 + n16) * 128 + ks * 32 + q * 8;
      float4 a = *(const float4*)xp;
      float4 b = *(const float4*)(xp + 4);
      union { short8 v; unsigned short u[8]; } H, L;
      float xv[8] = {a.x, a.y, a.z, a.w, b.x, b.y, b.z, b.w};
#pragma unroll
      for (int j = 0; j < 8; j++) bfsplit(xv[j], H.u[j], L.u[j]);
      ahi[mt] = H.v; alo[mt] = L.v;
    }
#pragma unroll
    for (int nt = 0; nt < 8; nt++) {
      int e = nt * 2048 + ks * 512 + lane * 8;
      short8 bh = *(const short8*)(tabhi + e);
      short8 bl = *(const short8*)(tablo + e);
#pragma unroll
      for (int mt = 0; mt < 2; mt++) {
        acc[mt][nt] = __builtin_amdgcn_mfma_f32_16x16x32_bf16(ahi[mt], bl, acc[mt][nt], 0, 0, 0);
        acc[mt][nt] = __builtin_amdgcn_mfma_f32_16x16x32_bf16(alo[mt], bh, acc[mt][nt], 0, 0, 0);
        acc[mt][nt] = __builtin_amdgcn_mfma_f32_16x16x32_bf16(ahi[mt], bh, acc[mt][nt], 0, 0, 0);
      }
    }
  }

#pragma unroll
  for (int mt = 0; mt < 2; mt++)
#pragma unroll
    for (int nt = 0; nt < 8; nt++) {
      int col = nt * 16 + n16;
      int rowb = wv * 32 + mt * 16 + q * 4;
#pragma unroll
      for (int rp = 0; rp < 4; rp += 2) {
        unsigned short h0, l0, h1, l1;
        bfsplit(acc[mt][nt][rp], h0, l0);
        bfsplit(acc[mt][nt][rp + 1], h1, l1);
        int widx = (col * 136 + rowb + rp) >> 1;
        ((unsigned int*)sThi)[widx] = (unsigned int)h0 | ((unsigned int)h1 << 16);
        ((unsigned int*)sTlo)[widx] = (unsigned int)l0 | ((unsigned int)l1 << 16);
      }
    }
  __syncthreads();

#pragma unroll
  for (int mt = 0; mt < 2; mt++)
#pragma unroll
    for (int nt = 0; nt < 8; nt++) acc[mt][nt] = (floatx4){0.f, 0.f, 0.f, 0.f};

#pragma unroll
  for (int ks = 0; ks < 4; ks++) {
    short8 ahi[2], alo[2];
#pragma unroll
    for (int mt = 0; mt < 2; mt++) {
      int e = (wv * 2 + mt) * 2048 + ks * 512 + lane * 8;
      ahi[mt] = *(const short8*)(tabhi + e);
      alo[mt] = *(const short8*)(tablo + e);
    }
#pragma unroll
    for (int nt = 0; nt < 8; nt++) {
      int off = (nt * 16 + n16) * 136 + ks * 32 + q * 8;
      short8 bh = *(const short8*)(sThi + off);
      short8 bl = *(const short8*)(sTlo + off);
#pragma unroll
      for (int mt = 0; mt < 2; mt++) {
        acc[mt][nt] = __builtin_amdgcn_mfma_f32_16x16x32_bf16(ahi[mt], bl, acc[mt][nt], 0, 0, 0);
        acc[mt][nt] = __builtin_amdgcn_mfma_f32_16x16x32_bf16(alo[mt], bh, acc[mt][nt], 0, 0, 0);
        acc[mt][nt] = __builtin_amdgcn_mfma_f32_16x16x32_bf16(ahi[mt], bh, acc[mt][nt], 0, 0, 0);
      }
    }
  }

#pragma unroll
  for (int mt = 0; mt < 2; mt++)
#pragma unroll
    for (int nt = 0; nt < 8; nt++) {
      int row0 = wv * 32 + mt * 16 + q * 4;
      int col = nt * 16 + n16;
#pragma unroll
      for (int r = 0; r < 4; r++) {
        size_t oi = (size_t)s * HW + (size_t)(row0 + r) * 128 + col;
        float v = acc[mt][nt][r];
        if (xres) v += xres[oi];
        Y[oi] = v;
      }
    }
}

// ---- separable angular DCT kernels (9-point passes, no spill) ----
// fwd pass 1 (along u): out[(U*9+v)*3+c] = sum_u Da[U][u] * in[(u*9+v)*3+c]
__global__ __launch_bounds__(256) void k_angu(const float* __restrict__ in,
                                              const float* __restrict__ DaF,
                                              float* __restrict__ out) {
  __shared__ float sDa[81];
  int t = threadIdx.x;
  if (t < 81) sDa[t] = DaF[t];
  __syncthreads();
  int idx = blockIdx.x * 256 + t;   // 27*HW
  int hw = idx & (HW - 1);
  int r = idx >> 14;
  int c = r % 3, v = r / 3;
  float f[9];
#pragma unroll
  for (int u = 0; u < 9; u++) f[u] = in[(size_t)((u * 9 + v) * 3 + c) * HW + hw];
#pragma unroll
  for (int U = 0; U < 9; U++) {
    float acc = 0.f;
#pragma unroll
    for (int u = 0; u < 9; u++) acc += sDa[U * 9 + u] * f[u];
    out[(size_t)((U * 9 + v) * 3 + c) * HW + hw] = acc;
  }
}

// fwd pass 2 (along v) + band gather + bf16 pack (channels-last padded-4)
__global__ __launch_bounds__(256) void k_angv(const float* __restrict__ in,
                                              const float* __restrict__ DaF,
                                              unsigned short* __restrict__ xf2b) {
  __shared__ float sDa[81];
  int t = threadIdx.x;
  if (t < 81) sDa[t] = DaF[t];
  __syncthreads();
  int idx = blockIdx.x * 256 + t;
  int hw = idx & (HW - 1);
  int r = idx >> 14;
  int c = r % 3, U = r / 3;
  float f[9];
#pragma unroll
  for (int v = 0; v < 9; v++) f[v] = in[(size_t)((U * 9 + v) * 3 + c) * HW + hw];
#pragma unroll
  for (int V = 0; V < 9; V++) {
    float acc = 0.f;
#pragma unroll
    for (int v = 0; v < 9; v++) acc += sDa[V * 9 + v] * f[v];
    size_t base = ((size_t)c_pos_uv[U * 9 + V] * HW + hw) * 4;
    xf2b[base + c] = f2bf(acc);
    if (c == 0) xf2b[base + 3] = 0;
  }
}

// inv pass 1 (along V) + band scatter read: out[(U*9+v)*3+c] = sum_V Da[V][v]*xrb[pos(U,V)]
__global__ __launch_bounds__(256) void k_angvi(const float* __restrict__ xrb,
                                               const float* __restrict__ DaF,
                                               float* __restrict__ out) {
  __shared__ float sDa[81];
  int t = threadIdx.x;
  if (t < 81) sDa[t] = DaF[t];
  __syncthreads();
  int idx = blockIdx.x * 256 + t;
  int hw = idx & (HW - 1);
  int r = idx >> 14;
  int c = r % 3, U = r / 3;
  float f[9];
#pragma unroll
  for (int V = 0; V < 9; V++)
    f[V] = xrb[((size_t)c_pos_uv[U * 9 + V] * 3 + c) * HW + hw];
#pragma unroll
  for (int v = 0; v < 9; v++) {
    float acc = 0.f;
#pragma unroll
    for (int V = 0; V < 9; V++) acc += sDa[V * 9 + v] * f[V];
    out[(size_t)((U * 9 + v) * 3 + c) * HW + hw] = acc;
  }
}

// inv pass 2 (along U): out[(u*9+v)*3+c] = sum_U Da[U][u]*in[(U*9+v)*3+c]
__global__ __launch_bounds__(256) void k_angui(const float* __restrict__ in,
                                               const float* __restrict__ DaF,
                                               float* __restrict__ out) {
  __shared__ float sDa[81];
  int t = threadIdx.x;
  if (t < 81) sDa[t] = DaF[t];
  __syncthreads();
  int idx = blockIdx.x * 256 + t;
  int hw = idx & (HW - 1);
  int r = idx >> 14;
  int c = r % 3, v = r / 3;
  float f[9];
#pragma unroll
  for (int U = 0; U < 9; U++) f[U] = in[(size_t)((U * 9 + v) * 3 + c) * HW + hw];
#pragma unroll
  for (int u = 0; u < 9; u++) {
    float acc = 0.f;
#pragma unroll
    for (int U = 0; U < 9; U++) acc += sDa[U * 9 + u] * f[U];
    out[(size_t)((u * 9 + v) * 3 + c) * HW + hw] = acc;
  }
}

// ---- MFMA implicit-GEMM 3x3x3 conv over one band position ----
// braw0/braw1 store the ACTIVATED value (with the consumer's alpha) so the
// next conv's LDS staging is a pure copy; raw is reconstructed via inverse
// PReLU (exact for alpha = 2^-k) for residual/epi. braw2 stores raw.
__global__ __launch_bounds__(256) void k_conv(const unsigned short* __restrict__ src,
                                              const unsigned short* __restrict__ prevAct,
                                              const unsigned short* __restrict__ Wmf,
                                              const float* __restrict__ BiF,
                                              const float* __restrict__ BbF,
                                              const float* __restrict__ AF,
                                              int sel,
                                              unsigned short* __restrict__ bout) {
  __shared__ unsigned short s_lds[12672];   // 25344 B
  int p = blockIdx.y;
  int s = c_s_of_p[p], l = c_l_of_p[p];
  int g = c_g_of_s[s], Ls = c_L_of_s[s];
  int row0 = blockIdx.x * 4;
  int t = threadIdx.x;
  int lane = t & 63, wv = t >> 6;
  int q = lane >> 4, n = lane & 15;

  float aNext = (sel < 2) ? AF[g * 2 + sel] : 0.f;       // consumer's alpha
  float invA  = (sel > 0) ? 1.0f / AF[g * 2 + sel - 1] : 0.f;  // this stage's alpha

  int basel = wv * 4224 + (q & 1) * 2112 + n * 16;
  int off2[5];
#pragma unroll
  for (int i = 0; i < 5; i++) {
    int tl = 2 * i + (q >> 1);
    if (tl > 8) tl = 8;
    int ky = tl / 3, kx = tl % 3;
    off2[i] = basel + ky * 4224 + kx * 16;
  }

  int setIdx = (sel == 0) ? g : (4 + g * 2 + (sel - 1));
  const char* WsetBase = (const char*)Wmf + (size_t)setIdx * 15 * 1024;

  floatx4 acc[8];
#pragma unroll
  for (int cg = 0; cg < 8; cg++) acc[cg] = (floatx4){0.f, 0.f, 0.f, 0.f};

  for (int d = 0; d < 3; d++) {
    int l2 = l + d - 1;
    if (l2 < 0 || l2 >= Ls) continue;
    int p2 = p + d - 1;
    __syncthreads();
    // ---- stage slab into LDS (pure copy; activation pre-applied) ----
    for (int c = t; c < 1560; c += 256) {
      int half = c & 1, cc = c >> 1;
      int col = cc % 130, row = cc / 130;
      int grow = row0 - 1 + row, gcol = col - 1;
      bool v = ((unsigned)grow < 128u) && ((unsigned)gcol < 128u);
      uint4v val = (uint4v){0u, 0u, 0u, 0u};
      if (sel == 0) {
        if (v && half == 0) {
          const unsigned int* sp = (const unsigned int*)(src) +
              ((size_t)p2 * HW + grow * 128 + gcol) * 2;
          val.x = sp[0]; val.y = sp[1];
        }
      } else {
        if (v) {
          val = *(const uint4v*)(src +
              (((size_t)p2 * HW + grow * 128 + gcol) * 16 + half * 8));
        }
      }
      *(uint4v*)((char*)s_lds + ((size_t)((row * 2 + half) * 132 + col)) * 16) = val;
    }
    __syncthreads();
    short8 af[5];
#pragma unroll
    for (int i = 0; i < 5; i++)
      af[i] = *(const short8*)(WsetBase + ((d * 5 + i) * 64 + lane) * 16);
#pragma unroll
    for (int cg = 0; cg < 8; cg++) {
#pragma unroll
      for (int i = 0; i < 5; i++) {
        short8 b = *(const short8*)((const char*)s_lds + off2[i] + cg * 256);
        acc[cg] = __builtin_amdgcn_mfma_f32_16x16x32_bf16(af[i], b, acc[cg], 0, 0, 0);
      }
    }
  }

  // ---- epilogue: bias (+ residual via inverse prelu), activate for consumer ----
  const float* bp = (sel == 0) ? (BiF + g * 16) : (BbF + g * 32 + (sel - 1) * 16);
  float bz[4];
#pragma unroll
  for (int r = 0; r < 4; r++) bz[r] = bp[q * 4 + r];
  int h = row0 + wv;
#pragma unroll
  for (int cg = 0; cg < 8; cg++) {
    size_t pix = (size_t)p * HW + h * 128 + cg * 16 + n;
    float r0 = acc[cg][0] + bz[0], r1 = acc[cg][1] + bz[1];
    float r2 = acc[cg][2] + bz[2], r3 = acc[cg][3] + bz[3];
    if (sel != 0) {
      uint2v pv = *(const uint2v*)(prevAct + pix * 16 + q * 4);
      r0 += invprelu(bflo(pv.x), invA); r1 += invprelu(bfhi(pv.x), invA);
      r2 += invprelu(bflo(pv.y), invA); r3 += invprelu(bfhi(pv.y), invA);
    }
    if (sel < 2) {   // store activated with consumer's alpha
      r0 = fmaxf(r0, 0.f) + aNext * fminf(r0, 0.f);
      r1 = fmaxf(r1, 0.f) + aNext * fminf(r1, 0.f);
      r2 = fmaxf(r2, 0.f) + aNext * fminf(r2, 0.f);
      r3 = fmaxf(r3, 0.f) + aNext * fminf(r3, 0.f);
    }
    uint2v ov; ov.x = pack2(r0, r1); ov.y = pack2(r2, r3);
    *(uint2v*)(bout + pix * 16 + q * 4) = ov;
  }
}

// ---- epilogue 1x1: xrb[p][c][hw] = sum_n Wl[c][n]*(raw0+raw2) ----
// b0 holds activated values (alpha = AF[g*2]); reconstruct raw via inverse prelu.
__global__ __launch_bounds__(256) void k_epi(const unsigned short* __restrict__ b0,
                                             const unsigned short* __restrict__ b2,
                                             const float* __restrict__ WlF,
                                             const float* __restrict__ AF,
                                             float* __restrict__ xrb) {
  int idx = blockIdx.x * 256 + threadIdx.x;  // 81*HW
  int hw = idx & (HW - 1);
  int p = idx >> 14;
  int g = c_g_of_s[c_s_of_p[p]];
  float invA0 = 1.0f / AF[g * 2];
  size_t base = ((size_t)p * HW + hw) * 16;
  uint4v a0 = *(const uint4v*)(b0 + base);
  uint4v a1 = *(const uint4v*)(b0 + base + 8);
  uint4v c0 = *(const uint4v*)(b2 + base);
  uint4v c1 = *(const uint4v*)(b2 + base + 8);
  float v[16];
  v[0]  = invprelu(bflo(a0.x), invA0) + bflo(c0.x);
  v[1]  = invprelu(bfhi(a0.x), invA0) + bfhi(c0.x);
  v[2]  = invprelu(bflo(a0.y), invA0) + bflo(c0.y);
  v[3]  = invprelu(bfhi(a0.y), invA0) + bfhi(c0.y);
  v[4]  = invprelu(bflo(a0.z), invA0) + bflo(c0.z);
  v[5]  = invprelu(bfhi(a0.z), invA0) + bfhi(c0.z);
  v[6]  = invprelu(bflo(a0.w), invA0) + bflo(c0.w);
  v[7]  = invprelu(bfhi(a0.w), invA0) + bfhi(c0.w);
  v[8]  = invprelu(bflo(a1.x), invA0) + bflo(c1.x);
  v[9]  = invprelu(bfhi(a1.x), invA0) + bfhi(c1.x);
  v[10] = invprelu(bflo(a1.y), invA0) + bflo(c1.y);
  v[11] = invprelu(bfhi(a1.y), invA0) + bfhi(c1.y);
  v[12] = invprelu(bflo(a1.z), invA0) + bflo(c1.z);
  v[13] = invprelu(bfhi(a1.z), invA0) + bfhi(c1.z);
  v[14] = invprelu(bflo(a1.w), invA0) + bflo(c1.w);
  v[15] = invprelu(bfhi(a1.w), invA0) + bfhi(c1.w);
  float o0 = 0.f, o1 = 0.f, o2 = 0.f;
#pragma unroll
  for (int k = 0; k < 16; k++) {
    o0 += WlF[k] * v[k]; o1 += WlF[16 + k] * v[k]; o2 += WlF[32 + k] * v[k];
  }
  xrb[((size_t)p * 3 + 0) * HW + hw] = o0;
  xrb[((size_t)p * 3 + 1) * HW + hw] = o1;
  xrb[((size_t)p * 3 + 2) * HW + hw] = o2;
}

extern "C" void kernel_launch(void* const* d_in, const int* in_sizes, int n_in,
                              void* d_out, int out_size, void* d_ws, size_t ws_size,
                              hipStream_t stream) {
  (void)in_sizes; (void)n_in; (void)out_size; (void)ws_size;
  const float* x = (const float*)d_in[0];
  WPtrs P;
  for (int g = 0; g < 4; g++) {
    int b = 1 + g * 5;
    P.wi[g] = (const float*)d_in[b + 0];
    P.bi[g] = (const float*)d_in[b + 1];
    P.a[g]  = (const float*)d_in[b + 2];
    P.wb[g] = (const float*)d_in[b + 3];
    P.bb[g] = (const float*)d_in[b + 4];
  }
  P.wl = (const float*)d_in[21];

  char* base = (char*)d_ws;
  size_t off = 0;
  auto take = [&](size_t bytes) -> char* {
    char* r = base + off;
    off += (bytes + 255) & ~(size_t)255;
    return r;
  };
  float* DaF = (float*)take(81 * 4);
  unsigned short* TFhi = (unsigned short*)take(16384 * 2);
  unsigned short* TFlo = (unsigned short*)take(16384 * 2);
  unsigned short* TIhi = (unsigned short*)take(16384 * 2);
  unsigned short* TIlo = (unsigned short*)take(16384 * 2);
  unsigned short* Wmf = (unsigned short*)take(92160 * 2);
  float* BiF   = (float*)take(256);
  float* BbF   = (float*)take(512);
  float* AF    = (float*)take(32);
  float* WlF   = (float*)take(192);
  float* R1 = (float*)take((size_t)NSLICE * HW * 4);   // dct2-fwd out | angui out
  float* R2 = (float*)take((size_t)NSLICE * HW * 4);   // angu tmp | angvi tmp
  float* R3 = (float*)take((size_t)NSLICE * HW * 4);   // xf2b (bf16) | xrb (f32)
  unsigned short* braw0 = (unsigned short*)take((size_t)81 * 16 * HW * 2);
  unsigned short* braw1 = (unsigned short*)take((size_t)81 * 16 * HW * 2);
  unsigned short* braw2 = (unsigned short*)take((size_t)81 * 16 * HW * 2);
  unsigned short* xf2b = (unsigned short*)R3;          // 10.6 MB < 15.9 MB
  float* xrb = R3;

  k_setup<<<64, 256, 0, stream>>>(DaF, TFhi, TFlo, TIhi, TIlo);
  k_prep<<<360, 256, 0, stream>>>(P, Wmf, BiF, BbF, AF, WlF);
  // fused forward spatial DCT (per-slice MFMA split-bf16)
  k_dct2<<<243, 256, 0, stream>>>(x, TFhi, TFlo, nullptr, R1);
  // forward angular DCT, separable + band gather -> channels-last bf16
  k_angu<<<1728, 256, 0, stream>>>(R1, DaF, R2);
  k_angv<<<1728, 256, 0, stream>>>(R2, DaF, xf2b);
  // branch convs (MFMA implicit GEMM; act-forwarding between stages)
  k_conv<<<dim3(32, 81), 256, 0, stream>>>(xf2b, nullptr, Wmf, BiF, BbF, AF, 0, braw0);
  k_conv<<<dim3(32, 81), 256, 0, stream>>>(braw0, braw0, Wmf, BiF, BbF, AF, 1, braw1);
  k_conv<<<dim3(32, 81), 256, 0, stream>>>(braw1, braw1, Wmf, BiF, BbF, AF, 2, braw2);
  // (raw0 + raw2) then folded 1x1 conv -> xrb
  k_epi<<<5184, 256, 0, stream>>>(braw0, braw2, WlF, AF, xrb);
  // inverse angular DCT, separable (band scatter in pass 1)
  k_angvi<<<1728, 256, 0, stream>>>(xrb, DaF, R2);
  k_angui<<<1728, 256, 0, stream>>>(R2, DaF, R1);
  // fused inverse spatial DCT + residual add
  k_dct2<<<243, 256, 0, stream>>>(R1, TIhi, TIlo, x, (float*)d_out);
}

// Round 6
// 299.330 us; speedup vs baseline: 5.0636x; 1.0601x over previous
//
#include <hip/hip_runtime.h>
#include <hip/hip_bf16.h>
#include <math.h>

typedef __hip_bfloat16 bf16;
typedef __attribute__((ext_vector_type(8))) short short8;
typedef __attribute__((ext_vector_type(4))) float floatx4;
typedef __attribute__((ext_vector_type(4))) unsigned int uint4v;
typedef __attribute__((ext_vector_type(2))) unsigned int uint2v;

#define HW 16384          // 128*128
#define NSLICE 243        // 9*9*3

// ---- band tables (anti-diagonals of 9x9 grid) ----
__constant__ int c_s_of_p[81] = {
  0, 1,1, 2,2,2, 3,3,3,3, 4,4,4,4,4, 5,5,5,5,5,5, 6,6,6,6,6,6,6,
  7,7,7,7,7,7,7,7, 8,8,8,8,8,8,8,8,8, 9,9,9,9,9,9,9,9,
  10,10,10,10,10,10,10, 11,11,11,11,11,11, 12,12,12,12,12,
  13,13,13,13, 14,14,14, 15,15, 16};
__constant__ int c_l_of_p[81] = {
  0, 0,1, 0,1,2, 0,1,2,3, 0,1,2,3,4, 0,1,2,3,4,5, 0,1,2,3,4,5,6,
  0,1,2,3,4,5,6,7, 0,1,2,3,4,5,6,7,8, 0,1,2,3,4,5,6,7,
  0,1,2,3,4,5,6, 0,1,2,3,4,5, 0,1,2,3,4, 0,1,2,3, 0,1,2, 0,1, 0};
__constant__ int c_L_of_s[17] = {1,2,3,4,5,6,7,8,9,8,7,6,5,4,3,2,1};
__constant__ int c_g_of_s[17] = {0,1,1,2,2,2,2,2,2,3,3,3,3,3,3,3,3};
__constant__ int c_pos_uv[81] = {
  0,1,3,6,10,15,21,28,36,
  2,4,7,11,16,22,29,37,45,
  5,8,12,17,23,30,38,46,53,
  9,13,18,24,31,39,47,54,60,
  14,19,25,32,40,48,55,61,66,
  20,26,33,41,49,56,62,67,71,
  27,34,42,50,57,63,68,72,75,
  35,43,51,58,64,69,73,76,78,
  44,52,59,65,70,74,77,79,80};

struct WPtrs {
  const float* wi[4]; const float* bi[4]; const float* a[4];
  const float* wb[4]; const float* bb[4]; const float* wl;
};

__device__ __forceinline__ unsigned short f2bf(float f) {
  return __bfloat16_as_ushort(__float2bfloat16(f));
}
__device__ __forceinline__ float bflo(unsigned int w) {
  return __uint_as_float(w << 16);
}
__device__ __forceinline__ float bfhi(unsigned int w) {
  return __uint_as_float(w & 0xffff0000u);
}
__device__ __forceinline__ unsigned int pack2(float a, float b) {
  return (unsigned int)f2bf(a) | ((unsigned int)f2bf(b) << 16);
}
// inverse PReLU: raw = v>=0 ? v : v*invA  (exact for alpha = power of two)
__device__ __forceinline__ float invprelu(float v, float invA) {
  return (v >= 0.f) ? v : v * invA;
}
// split fp32 into bf16 hi (truncate) + bf16 lo (RNE of remainder): ~2^-17 rel
__device__ __forceinline__ void bfsplit(float v, unsigned short& hi, unsigned short& lo) {
  unsigned int bits = __float_as_uint(v);
  hi = (unsigned short)(bits >> 16);
  lo = f2bf(v - __uint_as_float(bits & 0xffff0000u));
}

// ---- setup: 9-point angular DCT matrix + spatial-DCT MFMA fragment tables ----
__global__ __launch_bounds__(256) void k_setup(float* DaF,
                                               unsigned short* TFhi, unsigned short* TFlo,
                                               unsigned short* TIhi, unsigned short* TIlo) {
  const double PI = 3.14159265358979323846;
  int t = blockIdx.x * 256 + threadIdx.x;
  if (t < 81) {   // Da[U][u]
    int U = t / 9, u = t % 9;
    double d = cos(PI * (u + 0.5) * U / 9.0) * sqrt(2.0 / 9.0);
    if (U == 0) d *= (1.0 / sqrt(2.0));
    DaF[t] = (float)d;
  }
  if (t < 16384) {
    int jj = t & 7, lane = (t >> 3) & 63, ks = (t >> 9) & 3, tile = t >> 11;
    int row = tile * 16 + (lane & 15);
    int colk = ks * 32 + (lane >> 4) * 8 + jj;
    double vF = cos(PI * (colk + 0.5) * row / 128.0) * sqrt(2.0 / 128.0);
    if (row == 0) vF *= (1.0 / sqrt(2.0));
    double vI = cos(PI * (row + 0.5) * colk / 128.0) * sqrt(2.0 / 128.0);
    if (colk == 0) vI *= (1.0 / sqrt(2.0));
    unsigned short h, l;
    bfsplit((float)vF, h, l); TFhi[t] = h; TFlo[t] = l;
    bfsplit((float)vI, h, l); TIhi[t] = h; TIlo[t] = l;
  }
}

// ---- conv weight repack into MFMA A-fragment order (unchanged) ----
__global__ __launch_bounds__(256) void k_prep(WPtrs P, unsigned short* Wmf,
                                              float* BiF, float* BbF,
                                              float* AF, float* WlF) {
  int t = blockIdx.x * 256 + threadIdx.x;
  if (t < 92160) {
    int s = t / 7680, r = t % 7680;
    int step = r / 512, r2 = r % 512;
    int lane = r2 >> 3, j = r2 & 7;
    int d = step / 5, i = step % 5;
    int q = lane >> 4, m = lane & 15;
    int tl = 2 * i + (q >> 1);
    int cin = (q & 1) * 8 + j;
    float val = 0.f;
    if (tl <= 8) {
      int ky = tl / 3, kx = tl % 3;
      int tap = d * 9 + ky * 3 + kx;
      if (s < 4) {
        if (cin < 3) val = P.wi[s][(m * 3 + cin) * 27 + tap];
      } else {
        int g = (s - 4) >> 1, k = (s - 4) & 1;
        val = P.wb[g][((k * 16 + m) * 16 + cin) * 27 + tap];
      }
    }
    Wmf[t] = f2bf(val);
  }
  if (t < 64)  BiF[t] = P.bi[t / 16][t % 16];
  if (t < 128) BbF[t] = P.bb[t / 32][t % 32];
  if (t < 8)   AF[t]  = P.a[t / 2][t % 2];
  if (t < 48)  WlF[t] = P.wl[t];
}

// ---- fused spatial DCT: Y = Dop * X * Dop^T per 128x128 slice (unchanged) ----
__global__ __launch_bounds__(256) void k_dct2(const float* __restrict__ X,
                                              const unsigned short* __restrict__ tabhi,
                                              const unsigned short* __restrict__ tablo,
                                              const float* __restrict__ xres,
                                              float* __restrict__ Y) {
  __shared__ unsigned short sThi[128 * 136];
  __shared__ unsigned short sTlo[128 * 136];
  int s = blockIdx.x;
  int t = threadIdx.x;
  int lane = t & 63, wv = t >> 6;
  int q = lane >> 4, n16 = lane & 15;
  const float* Xs = X + (size_t)s * HW;

  floatx4 acc[2][8];
#pragma unroll
  for (int mt = 0; mt < 2; mt++)
#pragma unroll
    for (int nt = 0; nt < 8; nt++) acc[mt][nt] = (floatx4){0.f, 0.f, 0.f, 0.f};

#pragma unroll
  for (int ks = 0; ks < 4; ks++) {
    short8 ahi[2], alo[2];
#pragma unroll
    for (int mt = 0; mt < 2; mt++) {
      const float* xp = Xs + (wv * 32 + mt * 16 + n16) * 128 + ks * 32 + q * 8;
      float4 a = *(const float4*)xp;
      float4 b = *(const float4*)(xp + 4);
      union { short8 v; unsigned short u[8]; } H, L;
      float xv[8] = {a.x, a.y, a.z, a.w, b.x, b.y, b.z, b.w};
#pragma unroll
      for (int j = 0; j < 8; j++) bfsplit(xv[j], H.u[j], L.u[j]);
      ahi[mt] = H.v; alo[mt] = L.v;
    }
#pragma unroll
    for (int nt = 0; nt < 8; nt++) {
      int e = nt * 2048 + ks * 512 + lane * 8;
      short8 bh = *(const short8*)(tabhi + e);
      short8 bl = *(const short8*)(tablo + e);
#pragma unroll
      for (int mt = 0; mt < 2; mt++) {
        acc[mt][nt] = __builtin_amdgcn_mfma_f32_16x16x32_bf16(ahi[mt], bl, acc[mt][nt], 0, 0, 0);
        acc[mt][nt] = __builtin_amdgcn_mfma_f32_16x16x32_bf16(alo[mt], bh, acc[mt][nt], 0, 0, 0);
        acc[mt][nt] = __builtin_amdgcn_mfma_f32_16x16x32_bf16(ahi[mt], bh, acc[mt][nt], 0, 0, 0);
      }
    }
  }

#pragma unroll
  for (int mt = 0; mt < 2; mt++)
#pragma unroll
    for (int nt = 0; nt < 8; nt++) {
      int col = nt * 16 + n16;
      int rowb = wv * 32 + mt * 16 + q * 4;
#pragma unroll
      for (int rp = 0; rp < 4; rp += 2) {
        unsigned short h0, l0, h1, l1;
        bfsplit(acc[mt][nt][rp], h0, l0);
        bfsplit(acc[mt][nt][rp + 1], h1, l1);
        int widx = (col * 136 + rowb + rp) >> 1;
        ((unsigned int*)sThi)[widx] = (unsigned int)h0 | ((unsigned int)h1 << 16);
        ((unsigned int*)sTlo)[widx] = (unsigned int)l0 | ((unsigned int)l1 << 16);
      }
    }
  __syncthreads();

#pragma unroll
  for (int mt = 0; mt < 2; mt++)
#pragma unroll
    for (int nt = 0; nt < 8; nt++) acc[mt][nt] = (floatx4){0.f, 0.f, 0.f, 0.f};

#pragma unroll
  for (int ks = 0; ks < 4; ks++) {
    short8 ahi[2], alo[2];
#pragma unroll
    for (int mt = 0; mt < 2; mt++) {
      int e = (wv * 2 + mt) * 2048 + ks * 512 + lane * 8;
      ahi[mt] = *(const short8*)(tabhi + e);
      alo[mt] = *(const short8*)(tablo + e);
    }
#pragma unroll
    for (int nt = 0; nt < 8; nt++) {
      int off = (nt * 16 + n16) * 136 + ks * 32 + q * 8;
      short8 bh = *(const short8*)(sThi + off);
      short8 bl = *(const short8*)(sTlo + off);
#pragma unroll
      for (int mt = 0; mt < 2; mt++) {
        acc[mt][nt] = __builtin_amdgcn_mfma_f32_16x16x32_bf16(ahi[mt], bl, acc[mt][nt], 0, 0, 0);
        acc[mt][nt] = __builtin_amdgcn_mfma_f32_16x16x32_bf16(alo[mt], bh, acc[mt][nt], 0, 0, 0);
        acc[mt][nt] = __builtin_amdgcn_mfma_f32_16x16x32_bf16(ahi[mt], bh, acc[mt][nt], 0, 0, 0);
      }
    }
  }

#pragma unroll
  for (int mt = 0; mt < 2; mt++)
#pragma unroll
    for (int nt = 0; nt < 8; nt++) {
      int row0 = wv * 32 + mt * 16 + q * 4;
      int col = nt * 16 + n16;
#pragma unroll
      for (int r = 0; r < 4; r++) {
        size_t oi = (size_t)s * HW + (size_t)(row0 + r) * 128 + col;
        float v = acc[mt][nt][r];
        if (xres) v += xres[oi];
        Y[oi] = v;
      }
    }
}

// ---- separable angular DCT kernels (9-point passes, no spill) ----
__global__ __launch_bounds__(256) void k_angu(const float* __restrict__ in,
                                              const float* __restrict__ DaF,
                                              float* __restrict__ out) {
  __shared__ float sDa[81];
  int t = threadIdx.x;
  if (t < 81) sDa[t] = DaF[t];
  __syncthreads();
  int idx = blockIdx.x * 256 + t;   // 27*HW
  int hw = idx & (HW - 1);
  int r = idx >> 14;
  int c = r % 3, v = r / 3;
  float f[9];
#pragma unroll
  for (int u = 0; u < 9; u++) f[u] = in[(size_t)((u * 9 + v) * 3 + c) * HW + hw];
#pragma unroll
  for (int U = 0; U < 9; U++) {
    float acc = 0.f;
#pragma unroll
    for (int u = 0; u < 9; u++) acc += sDa[U * 9 + u] * f[u];
    out[(size_t)((U * 9 + v) * 3 + c) * HW + hw] = acc;
  }
}

__global__ __launch_bounds__(256) void k_angv(const float* __restrict__ in,
                                              const float* __restrict__ DaF,
                                              unsigned short* __restrict__ xf2b) {
  __shared__ float sDa[81];
  int t = threadIdx.x;
  if (t < 81) sDa[t] = DaF[t];
  __syncthreads();
  int idx = blockIdx.x * 256 + t;
  int hw = idx & (HW - 1);
  int r = idx >> 14;
  int c = r % 3, U = r / 3;
  float f[9];
#pragma unroll
  for (int v = 0; v < 9; v++) f[v] = in[(size_t)((U * 9 + v) * 3 + c) * HW + hw];
#pragma unroll
  for (int V = 0; V < 9; V++) {
    float acc = 0.f;
#pragma unroll
    for (int v = 0; v < 9; v++) acc += sDa[V * 9 + v] * f[v];
    size_t base = ((size_t)c_pos_uv[U * 9 + V] * HW + hw) * 4;
    xf2b[base + c] = f2bf(acc);
    if (c == 0) xf2b[base + 3] = 0;
  }
}

__global__ __launch_bounds__(256) void k_angvi(const float* __restrict__ xrb,
                                               const float* __restrict__ DaF,
                                               float* __restrict__ out) {
  __shared__ float sDa[81];
  int t = threadIdx.x;
  if (t < 81) sDa[t] = DaF[t];
  __syncthreads();
  int idx = blockIdx.x * 256 + t;
  int hw = idx & (HW - 1);
  int r = idx >> 14;
  int c = r % 3, U = r / 3;
  float f[9];
#pragma unroll
  for (int V = 0; V < 9; V++)
    f[V] = xrb[((size_t)c_pos_uv[U * 9 + V] * 3 + c) * HW + hw];
#pragma unroll
  for (int v = 0; v < 9; v++) {
    float acc = 0.f;
#pragma unroll
    for (int V = 0; V < 9; V++) acc += sDa[V * 9 + v] * f[V];
    out[(size_t)((U * 9 + v) * 3 + c) * HW + hw] = acc;
  }
}

__global__ __launch_bounds__(256) void k_angui(const float* __restrict__ in,
                                               const float* __restrict__ DaF,
                                               float* __restrict__ out) {
  __shared__ float sDa[81];
  int t = threadIdx.x;
  if (t < 81) sDa[t] = DaF[t];
  __syncthreads();
  int idx = blockIdx.x * 256 + t;
  int hw = idx & (HW - 1);
  int r = idx >> 14;
  int c = r % 3, v = r / 3;
  float f[9];
#pragma unroll
  for (int U = 0; U < 9; U++) f[U] = in[(size_t)((U * 9 + v) * 3 + c) * HW + hw];
#pragma unroll
  for (int u = 0; u < 9; u++) {
    float acc = 0.f;
#pragma unroll
    for (int U = 0; U < 9; U++) acc += sDa[U * 9 + u] * f[U];
    out[(size_t)((u * 9 + v) * 3 + c) * HW + hw] = acc;
  }
}

// ---- MFMA implicit-GEMM 3x3x3 conv, 8 output rows per 512-thread block ----
// Staging is shift-based: col = t&127 and half = (t>>7)&1 are iteration-
// invariant; row advances by 2. Halo cols 0/129 (and sel0's cin8..15 plane)
// are statically pre-zeroed. sel=2 fuses the (raw0 + y2) 1x1 w_last epilogue
// (butterfly over quads) and writes xrb directly.
__global__ __launch_bounds__(512) void k_conv(const unsigned short* __restrict__ src,
                                              const unsigned short* __restrict__ prevAct,
                                              const unsigned short* __restrict__ act0,
                                              const unsigned short* __restrict__ Wmf,
                                              const float* __restrict__ BiF,
                                              const float* __restrict__ BbF,
                                              const float* __restrict__ AF,
                                              const float* __restrict__ WlF,
                                              int sel,
                                              unsigned short* __restrict__ boutAct,
                                              float* __restrict__ xrbOut) {
  __shared__ unsigned short s_lds[10 * 132 * 16];   // 42240 B
  int p = blockIdx.y;
  int s = c_s_of_p[p], l = c_l_of_p[p];
  int g = c_g_of_s[s], Ls = c_L_of_s[s];
  int row0 = blockIdx.x * 8;
  int t = threadIdx.x;
  int lane = t & 63, wv = t >> 6;       // wv 0..7
  int q = lane >> 4, n = lane & 15;

  float aNext = (sel < 2) ? AF[g * 2 + sel] : 0.f;
  float invA  = (sel > 0) ? 1.0f / AF[g * 2 + sel - 1] : 0.f;

  // staging invariants
  int scol = t & 127;
  int shalf = (t >> 7) & 1;
  int srow0 = t >> 8;                   // 0 or 1

  // ---- static zero region: halo cols 0/129; sel0 also zeroes half==1 plane ----
  {
    uint4v z = (uint4v){0u, 0u, 0u, 0u};
    int zmax = (sel == 0) ? 1320 : 40;
    for (int i = t; i < zmax; i += 512) {
      int row, half, col;
      if (i < 40) { row = i >> 2; half = (i >> 1) & 1; col = (i & 1) ? 129 : 0; }
      else { int j = i - 40; row = j >> 7; col = (j & 127) + 1; half = 1; }
      *(uint4v*)((char*)s_lds + (size_t)(((row * 2 + half) * 132 + col)) * 16) = z;
    }
  }

  // per-lane B-read offsets (bytes) for the 5 K-steps of a dz phase
  int basel = wv * 4224 + (q & 1) * 2112 + n * 16;
  int off2[5];
#pragma unroll
  for (int i = 0; i < 5; i++) {
    int tl = 2 * i + (q >> 1);
    if (tl > 8) tl = 8;
    int ky = tl / 3, kx = tl % 3;
    off2[i] = basel + ky * 4224 + kx * 16;
  }

  int setIdx = (sel == 0) ? g : (4 + g * 2 + (sel - 1));
  const char* WsetBase = (const char*)Wmf + (size_t)setIdx * 15 * 1024;

  floatx4 acc[8];
#pragma unroll
  for (int cg = 0; cg < 8; cg++) acc[cg] = (floatx4){0.f, 0.f, 0.f, 0.f};

  for (int d = 0; d < 3; d++) {
    int l2 = l + d - 1;
    if (l2 < 0 || l2 >= Ls) continue;     // block-uniform
    int p2 = p + d - 1;
    __syncthreads();
    // ---- stage slab interior ----
    if (sel == 0) {
      if (shalf == 0) {
#pragma unroll
        for (int it = 0; it < 5; it++) {
          int row = srow0 + it * 2;
          int grow = row0 - 1 + row;
          uint2v v2 = (uint2v){0u, 0u};
          if ((unsigned)grow < 128u)
            v2 = *(const uint2v*)(src + ((size_t)p2 * HW + grow * 128 + scol) * 4);
          uint4v val; val.x = v2.x; val.y = v2.y; val.z = 0u; val.w = 0u;
          *(uint4v*)((char*)s_lds + (size_t)((row * 2) * 132 + scol + 1) * 16) = val;
        }
      }
    } else {
#pragma unroll
      for (int it = 0; it < 5; it++) {
        int row = srow0 + it * 2;
        int grow = row0 - 1 + row;
        uint4v val = (uint4v){0u, 0u, 0u, 0u};
        if ((unsigned)grow < 128u)
          val = *(const uint4v*)(src +
              (((size_t)p2 * HW + grow * 128 + scol) * 16 + shalf * 8));
        *(uint4v*)((char*)s_lds + (size_t)((row * 2 + shalf) * 132 + scol + 1) * 16) = val;
      }
    }
    __syncthreads();
    // ---- A fragments + MFMA ----
    short8 af[5];
#pragma unroll
    for (int i = 0; i < 5; i++)
      af[i] = *(const short8*)(WsetBase + ((d * 5 + i) * 64 + lane) * 16);
#pragma unroll
    for (int cg = 0; cg < 8; cg++) {
#pragma unroll
      for (int i = 0; i < 5; i++) {
        short8 b = *(const short8*)((const char*)s_lds + off2[i] + cg * 256);
        acc[cg] = __builtin_amdgcn_mfma_f32_16x16x32_bf16(af[i], b, acc[cg], 0, 0, 0);
      }
    }
  }

  // ---- epilogue ----
  const float* bp = (sel == 0) ? (BiF + g * 16) : (BbF + g * 32 + (sel - 1) * 16);
  float bz[4];
#pragma unroll
  for (int r = 0; r < 4; r++) bz[r] = bp[q * 4 + r];
  int h = row0 + wv;

  if (sel < 2) {
#pragma unroll
    for (int cg = 0; cg < 8; cg++) {
      size_t pix = (size_t)p * HW + h * 128 + cg * 16 + n;
      float r0 = acc[cg][0] + bz[0], r1 = acc[cg][1] + bz[1];
      float r2 = acc[cg][2] + bz[2], r3 = acc[cg][3] + bz[3];
      if (sel != 0) {
        uint2v pv = *(const uint2v*)(prevAct + pix * 16 + q * 4);
        r0 += invprelu(bflo(pv.x), invA); r1 += invprelu(bfhi(pv.x), invA);
        r2 += invprelu(bflo(pv.y), invA); r3 += invprelu(bfhi(pv.y), invA);
      }
      // store activated with consumer's alpha
      r0 = fmaxf(r0, 0.f) + aNext * fminf(r0, 0.f);
      r1 = fmaxf(r1, 0.f) + aNext * fminf(r1, 0.f);
      r2 = fmaxf(r2, 0.f) + aNext * fminf(r2, 0.f);
      r3 = fmaxf(r3, 0.f) + aNext * fminf(r3, 0.f);
      uint2v ov; ov.x = pack2(r0, r1); ov.y = pack2(r2, r3);
      *(uint2v*)(boutAct + pix * 16 + q * 4) = ov;
    }
  } else {
    // fused (raw0 + y2) 1x1 w_last -> xrb[p][c][hw]
    float invA0 = 1.0f / AF[g * 2];
    float wl0[4], wl1[4], wl2[4];
#pragma unroll
    for (int r = 0; r < 4; r++) {
      wl0[r] = WlF[q * 4 + r];
      wl1[r] = WlF[16 + q * 4 + r];
      wl2[r] = WlF[32 + q * 4 + r];
    }
#pragma unroll
    for (int cg = 0; cg < 8; cg++) {
      size_t pix = (size_t)p * HW + h * 128 + cg * 16 + n;
      float r0 = acc[cg][0] + bz[0], r1 = acc[cg][1] + bz[1];
      float r2 = acc[cg][2] + bz[2], r3 = acc[cg][3] + bz[3];
      uint2v pv = *(const uint2v*)(prevAct + pix * 16 + q * 4);
      r0 += invprelu(bflo(pv.x), invA); r1 += invprelu(bfhi(pv.x), invA);
      r2 += invprelu(bflo(pv.y), invA); r3 += invprelu(bfhi(pv.y), invA);
      uint2v p0 = *(const uint2v*)(act0 + pix * 16 + q * 4);
      r0 += invprelu(bflo(p0.x), invA0); r1 += invprelu(bfhi(p0.x), invA0);
      r2 += invprelu(bflo(p0.y), invA0); r3 += invprelu(bfhi(p0.y), invA0);
      float o0 = wl0[0] * r0 + wl0[1] * r1 + wl0[2] * r2 + wl0[3] * r3;
      float o1 = wl1[0] * r0 + wl1[1] * r1 + wl1[2] * r2 + wl1[3] * r3;
      float o2 = wl2[0] * r0 + wl2[1] * r1 + wl2[2] * r2 + wl2[3] * r3;
      o0 += __shfl_xor(o0, 16); o0 += __shfl_xor(o0, 32);
      o1 += __shfl_xor(o1, 16); o1 += __shfl_xor(o1, 32);
      o2 += __shfl_xor(o2, 16); o2 += __shfl_xor(o2, 32);
      if (q == 0) {
        size_t hw = (size_t)h * 128 + cg * 16 + n;
        xrbOut[((size_t)p * 3 + 0) * HW + hw] = o0;
        xrbOut[((size_t)p * 3 + 1) * HW + hw] = o1;
        xrbOut[((size_t)p * 3 + 2) * HW + hw] = o2;
      }
    }
  }
}

extern "C" void kernel_launch(void* const* d_in, const int* in_sizes, int n_in,
                              void* d_out, int out_size, void* d_ws, size_t ws_size,
                              hipStream_t stream) {
  (void)in_sizes; (void)n_in; (void)out_size; (void)ws_size;
  const float* x = (const float*)d_in[0];
  WPtrs P;
  for (int g = 0; g < 4; g++) {
    int b = 1 + g * 5;
    P.wi[g] = (const float*)d_in[b + 0];
    P.bi[g] = (const float*)d_in[b + 1];
    P.a[g]  = (const float*)d_in[b + 2];
    P.wb[g] = (const float*)d_in[b + 3];
    P.bb[g] = (const float*)d_in[b + 4];
  }
  P.wl = (const float*)d_in[21];

  char* base = (char*)d_ws;
  size_t off = 0;
  auto take = [&](size_t bytes) -> char* {
    char* r = base + off;
    off += (bytes + 255) & ~(size_t)255;
    return r;
  };
  float* DaF = (float*)take(81 * 4);
  unsigned short* TFhi = (unsigned short*)take(16384 * 2);
  unsigned short* TFlo = (unsigned short*)take(16384 * 2);
  unsigned short* TIhi = (unsigned short*)take(16384 * 2);
  unsigned short* TIlo = (unsigned short*)take(16384 * 2);
  unsigned short* Wmf = (unsigned short*)take(92160 * 2);
  float* BiF   = (float*)take(256);
  float* BbF   = (float*)take(512);
  float* AF    = (float*)take(32);
  float* WlF   = (float*)take(192);
  float* R1 = (float*)take((size_t)NSLICE * HW * 4);   // dct2-fwd out | angui out
  float* R2 = (float*)take((size_t)NSLICE * HW * 4);   // angu tmp | angvi tmp
  float* R3 = (float*)take((size_t)NSLICE * HW * 4);   // xf2b (bf16) | xrb (f32)
  unsigned short* braw0 = (unsigned short*)take((size_t)81 * 16 * HW * 2);
  unsigned short* braw1 = (unsigned short*)take((size_t)81 * 16 * HW * 2);
  unsigned short* xf2b = (unsigned short*)R3;          // 10.6 MB < 15.9 MB
  float* xrb = R3;

  k_setup<<<64, 256, 0, stream>>>(DaF, TFhi, TFlo, TIhi, TIlo);
  k_prep<<<360, 256, 0, stream>>>(P, Wmf, BiF, BbF, AF, WlF);
  // fused forward spatial DCT (per-slice MFMA split-bf16)
  k_dct2<<<243, 256, 0, stream>>>(x, TFhi, TFlo, nullptr, R1);
  // forward angular DCT, separable + band gather -> channels-last bf16
  k_angu<<<1728, 256, 0, stream>>>(R1, DaF, R2);
  k_angv<<<1728, 256, 0, stream>>>(R2, DaF, xf2b);
  // branch convs (MFMA implicit GEMM; act-forwarding; sel2 fuses 1x1 epi)
  k_conv<<<dim3(16, 81), 512, 0, stream>>>(xf2b, nullptr, nullptr, Wmf,
                                           BiF, BbF, AF, WlF, 0, braw0, nullptr);
  k_conv<<<dim3(16, 81), 512, 0, stream>>>(braw0, braw0, nullptr, Wmf,
                                           BiF, BbF, AF, WlF, 1, braw1, nullptr);
  k_conv<<<dim3(16, 81), 512, 0, stream>>>(braw1, braw1, braw0, Wmf,
                                           BiF, BbF, AF, WlF, 2, nullptr, xrb);
  // inverse angular DCT, separable (band scatter in pass 1)
  k_angvi<<<1728, 256, 0, stream>>>(xrb, DaF, R2);
  k_angui<<<1728, 256, 0, stream>>>(R2, DaF, R1);
  // fused inverse spatial DCT + residual add
  k_dct2<<<243, 256, 0, stream>>>(R1, TIhi, TIlo, x, (float*)d_out);
}